// Round 4
// baseline (525.744 us; speedup 1.0000x reference)
//
#include <hip/hip_runtime.h>
#include <hip/hip_bf16.h>

typedef __hip_bfloat16 bf16;
typedef __attribute__((ext_vector_type(8))) short short8;
typedef __attribute__((ext_vector_type(4))) float f32x4;

#define SS 512
#define HD 768
#define NEGC (-1e30f)
#define NSPLIT 16
#define TOK 32                 // SS / NSPLIT
#define POOL_BLOCKS 1536       // 48 groups * 2 batch * 16 splits

// bf16 weight blob offsets (elements)
#define WOFF_NER 0
#define WOFF_EMD 1204224
#define WOFF_RW1 2408448
#define WOFF_CW1 4227072
#define WOFF_RW2 6045696
#define WOFF_CW2 6635520
#define W_TOT    7225344
#define CVT_UNITS (W_TOT / 1024)   // 7056 units of 1024 elems

// ---------------------------------------------------------------------------
// Device-scope grid barrier (sense-reversal via generation counter).
// State in __device__ globals: zero at module load; cnt returns to 0 after
// every barrier and gen only grows, so graph replays are safe.
// ---------------------------------------------------------------------------
__device__ unsigned d_cnt = 0;
__device__ unsigned d_gen = 0;

__device__ __forceinline__ void grid_bar(int nblk)
{
  __syncthreads();
  if (threadIdx.x == 0) {
    __threadfence();
    unsigned g = atomicAdd(&d_gen, 0u);
    unsigned t = atomicAdd(&d_cnt, 1u);
    if (t == (unsigned)(nblk - 1)) {
      atomicExch(&d_cnt, 0u);
      __threadfence();
      atomicAdd(&d_gen, 1u);
    } else {
      while (atomicAdd(&d_gen, 0u) == g) { __builtin_amdgcn_s_sleep(2); }
    }
    __threadfence();
  }
  __syncthreads();
}

// ---------------------------------------------------------------------------
// Dispatch 1: weight f32->bf16 convert (grid-stride prologue) + pooling.
// 1536 blocks x 256: 6 blocks/CU -> 75% occupancy for the latency-bound pool.
// Pool: 8 spans/block, 32 tokens (split sp of 16), all 768 h (3/thread).
// ---------------------------------------------------------------------------
__global__ __launch_bounds__(256) void k_pool_cvt(
    const int* __restrict__ e_masks, const int* __restrict__ m_masks,
    const int* __restrict__ r_masks, const int* __restrict__ c_masks,
    const float* __restrict__ emb, bf16* __restrict__ part, int* __restrict__ flags,
    const float* __restrict__ s0, const float* __restrict__ s1,
    const float* __restrict__ s2, const float* __restrict__ s3,
    const float* __restrict__ s4, const float* __restrict__ s5,
    bf16* __restrict__ wdst)
{
  int bx = blockIdx.x;
  int t  = threadIdx.x;

  // ---- weight convert, grid-stride over 1024-elem units ----
  for (int u = bx; u < CVT_UNITS; u += POOL_BLOCKS) {
    size_t i = ((size_t)u * 256 + t) * 4;
    const float* s; size_t off;
    if      (i < WOFF_EMD) { s = s0; off = i; }
    else if (i < WOFF_RW1) { s = s1; off = i - WOFF_EMD; }
    else if (i < WOFF_CW1) { s = s2; off = i - WOFF_RW1; }
    else if (i < WOFF_RW2) { s = s3; off = i - WOFF_CW1; }
    else if (i < WOFF_CW2) { s = s4; off = i - WOFF_RW2; }
    else                   { s = s5; off = i - WOFF_CW2; }
    float4 v = *(const float4*)(s + off);
    wdst[i]     = __hip_bfloat16(v.x);
    wdst[i + 1] = __hip_bfloat16(v.y);
    wdst[i + 2] = __hip_bfloat16(v.z);
    wdst[i + 3] = __hip_bfloat16(v.w);
  }

  // ---- pooling ----
  int g  = bx % 48;              // span group (8 spans)
  int b  = (bx / 48) & 1;        // batch
  int sp = bx / 96;              // S-split 0..15 (32 tokens each)
  int j0 = g * 8;

  const int* marr; int row0;
  if      (j0 < 64)  { marr = e_masks; row0 = b*64  +  j0;        }
  else if (j0 < 128) { marr = m_masks; row0 = b*64  + (j0-64);    }
  else if (j0 < 256) { marr = r_masks; row0 = b*128 + (j0-128);   }
  else               { marr = c_masks; row0 = b*128 + (j0-256);   }

  __shared__ unsigned s_pack[TOK];
  __shared__ unsigned s_any;
  if (t == 0) s_any = 0u;
  __syncthreads();

  int sbase = sp * TOK;
  if (t < TOK) {
    unsigned w = 0;
    #pragma unroll
    for (int k = 0; k < 8; k++) {
      int mm = marr[(size_t)(row0 + k) * SS + sbase + t];
      w |= (mm != 0 ? 1u : 0u) << k;
    }
    s_pack[t] = w;
    atomicOr(&s_any, w);
  }
  __syncthreads();

  float acc[8][3];
  #pragma unroll
  for (int k = 0; k < 8; k++)
    #pragma unroll
    for (int i = 0; i < 3; i++) acc[k][i] = -INFINITY;

  const float* ebase = emb + ((size_t)b * SS + sbase) * HD;
  for (int s = 0; s < TOK; s++) {
    unsigned wm = s_pack[s];
    const float* ep = ebase + (size_t)s * HD + t;
    float v0 = ep[0];
    float v1 = ep[256];
    float v2 = ep[512];
    #pragma unroll
    for (int k = 0; k < 8; k++) {
      float add = ((wm >> k) & 1u) ? 0.f : NEGC;
      acc[k][0] = fmaxf(acc[k][0], v0 + add);
      acc[k][1] = fmaxf(acc[k][1], v1 + add);
      acc[k][2] = fmaxf(acc[k][2], v2 + add);
    }
  }

  #pragma unroll
  for (int k = 0; k < 8; k++) {
    int sg = b * 384 + j0 + k;
    bf16* dst = part + ((size_t)sp * 768 + sg) * HD;
    dst[t]       = __hip_bfloat16(acc[k][0]);
    dst[t + 256] = __hip_bfloat16(acc[k][1]);
    dst[t + 512] = __hip_bfloat16(acc[k][2]);
  }
  if (t < 8) flags[sp * 768 + b * 384 + j0 + t] = (int)((s_any >> t) & 1u);
}

// ---------------------------------------------------------------------------
// Mega-kernel plumbing
// ---------------------------------------------------------------------------
struct GemmArgs { const void* A; const void* W; const float* bias; void* C; int K; int M; int store_bf16; };

struct MegaArgs {
  const bf16* part; const int* flags;
  bf16 *epool, *mpool, *rctx, *cctx;
  const int* input_ids; const float* emb;
  const int *esizes, *msizes;
  const float *nsemb, *esemb;
  const int *relations, *references;
  bf16 *nrep, *erep, *rrep, *crep;
  GemmArgs g1[4];
  GemmArgs g2[2];
  const float *NH, *EH, *RH2, *CH2;
  const float *nhw, *nhb, *ehw, *ehb, *rw3, *rb3, *cw3, *cb3;
  float* out;
};

// GEMM tile: C[32x32] = relu(A[Mt,K] @ W^T + bias). 4 waves split K, LDS-reduce.
__device__ __forceinline__ void gemm_stage(const GemmArgs& g, int x, int y, float* smem)
{
  int mt = x * 32;
  if (mt >= g.M) return;                 // block-uniform
  int nt = y * 32;
  const short* A = (const short*)g.A;
  const short* W = (const short*)g.W;
  int K_ = g.K;

  int wave = threadIdx.x >> 6, lane = threadIdx.x & 63;
  int lm = lane & 15, quad = lane >> 4;

  const short* a0p = A + (size_t)(mt + lm)      * K_ + quad * 8;
  const short* a1p = A + (size_t)(mt + 16 + lm) * K_ + quad * 8;
  const short* w0p = W + (size_t)(nt + lm)      * K_ + quad * 8;
  const short* w1p = W + (size_t)(nt + 16 + lm) * K_ + quad * 8;

  f32x4 acc00 = {0.f,0.f,0.f,0.f}, acc01 = {0.f,0.f,0.f,0.f};
  f32x4 acc10 = {0.f,0.f,0.f,0.f}, acc11 = {0.f,0.f,0.f,0.f};

  for (int k0 = wave * 32; k0 < K_; k0 += 128) {
    short8 a0 = *(const short8*)(a0p + k0);
    short8 a1 = *(const short8*)(a1p + k0);
    short8 w0 = *(const short8*)(w0p + k0);
    short8 w1 = *(const short8*)(w1p + k0);
    acc00 = __builtin_amdgcn_mfma_f32_16x16x32_bf16(a0, w0, acc00, 0, 0, 0);
    acc01 = __builtin_amdgcn_mfma_f32_16x16x32_bf16(a0, w1, acc01, 0, 0, 0);
    acc10 = __builtin_amdgcn_mfma_f32_16x16x32_bf16(a1, w0, acc10, 0, 0, 0);
    acc11 = __builtin_amdgcn_mfma_f32_16x16x32_bf16(a1, w1, acc11, 0, 0, 0);
  }

  // smem as [4][32][32]
  #pragma unroll
  for (int reg = 0; reg < 4; reg++) {
    int r = quad * 4 + reg;
    smem[wave*1024 + r*32 + lm]             = acc00[reg];
    smem[wave*1024 + r*32 + 16 + lm]        = acc01[reg];
    smem[wave*1024 + (16 + r)*32 + lm]      = acc10[reg];
    smem[wave*1024 + (16 + r)*32 + 16 + lm] = acc11[reg];
  }
  __syncthreads();

  int c = threadIdx.x & 31;
  int rb = threadIdx.x >> 5;
  float bb = g.bias[nt + c];
  #pragma unroll
  for (int i = 0; i < 4; i++) {
    int r = rb + 8 * i;
    float v = smem[r*32 + c] + smem[1024 + r*32 + c] + smem[2048 + r*32 + c] + smem[3072 + r*32 + c];
    v = fmaxf(v + bb, 0.f);
    if (g.store_bf16) ((bf16*)g.C)[(size_t)(mt + r) * HD + nt + c] = __hip_bfloat16(v);
    else              ((float*)g.C)[(size_t)(mt + r) * HD + nt + c] = v;
  }
  __syncthreads();   // protect smem before any reuse
}

// ---------------------------------------------------------------------------
// Mega-kernel: combine -> rep -> gemm L1 -> gemm L2 -> heads, with grid
// barriers. 768 blocks x 256 thr; __launch_bounds__(256,3) guarantees
// 3 blocks/CU so all 768 are co-resident (256 CU x 3).
// ---------------------------------------------------------------------------
#define MEGA_BLOCKS 768

__global__ __launch_bounds__(256, 3) void k_mega(MegaArgs a)
{
  __shared__ float smem[4 * 32 * 32];   // 16 KB, reused per stage
  __shared__ int s_cls;
  int t = threadIdx.x;

  // ================= stage 1: combine splits =================
  {
    int sg = blockIdx.x;
    int b = sg / 384, j = sg % 384;
    int any = 0;
    #pragma unroll
    for (int sp = 0; sp < NSPLIT; sp++) any |= a.flags[sp * 768 + sg];
    #pragma unroll
    for (int i = 0; i < 3; i++) {
      int h = t + i * 256;
      float v = -INFINITY;
      #pragma unroll
      for (int sp = 0; sp < NSPLIT; sp++)
        v = fmaxf(v, (float)a.part[((size_t)sp * 768 + sg) * HD + h]);
      if      (j < 64)  a.epool[((size_t)b*64  + j)       * HD + h] = __hip_bfloat16(v);
      else if (j < 128) a.mpool[((size_t)b*64  + (j-64))  * HD + h] = __hip_bfloat16(v);
      else if (j < 256) a.rctx [((size_t)b*128 + (j-128)) * HD + h] = __hip_bfloat16(any ? v : 0.f);
      else              a.cctx [((size_t)b*128 + (j-256)) * HD + h] = __hip_bfloat16(any ? v : 0.f);
    }
  }
  grid_bar(MEGA_BLOCKS);

  // ================= stage 2: rep builds (1024 units) =================
  for (int u = blockIdx.x; u < 1024; u += MEGA_BLOCKS) {
    int mode = u >> 8, x = u & 255;
    if (mode < 2) {
      if (x >= 128) continue;            // block-uniform
      int which = mode;
      int row = x;                       // b*64 + e
      int b = row >> 6;
      const bf16*  pool  = which ? a.mpool  : a.epool;
      const int*   sizes = which ? a.msizes : a.esizes;
      const float* st    = which ? a.esemb  : a.nsemb;
      bf16* rep = (which ? a.erep : a.nrep) + (size_t)row * 1568;

      if (t == 0) s_cls = SS;
      __syncthreads();
      for (int s = t; s < SS; s += 256)
        if (a.input_ids[b * SS + s] == 101) atomicMin(&s_cls, s);
      __syncthreads();
      int ci = (s_cls == SS) ? 0 : s_cls;

      const float* ctx = a.emb + ((size_t)b * SS + ci) * HD;
      const bf16*  pl  = pool + (size_t)row * HD;
      for (int h = t; h < HD; h += 256) {
        rep[h]       = __hip_bfloat16(ctx[h]);
        rep[768 + h] = pl[h];
      }
      if (t < 32)
        rep[1536 + t] = __hip_bfloat16(st[(size_t)sizes[row] * 32 + t]);
      __syncthreads();
    } else {
      int which = mode - 2;
      int row = x;                       // b*128 + r
      int b = row >> 7;
      const int*   rel   = which ? a.references : a.relations;
      const bf16*  ctx   = which ? a.cctx   : a.rctx;
      const bf16*  pool  = which ? a.mpool  : a.epool;
      const int*   sizes = which ? a.msizes : a.esizes;
      const float* st    = which ? a.esemb  : a.nsemb;
      bf16* rep = (which ? a.crep : a.rrep) + (size_t)row * 2368;

      int a0 = rel[row * 2], a1 = rel[row * 2 + 1];
      const bf16* p0 = pool + ((size_t)b * 64 + a0) * HD;
      const bf16* p1 = pool + ((size_t)b * 64 + a1) * HD;
      const bf16* cx = ctx + (size_t)row * HD;
      for (int h = t; h < HD; h += 256) {
        rep[h]        = cx[h];
        rep[768 + h]  = p0[h];
        rep[1536 + h] = p1[h];
      }
      if (t < 32) {
        rep[2304 + t] = __hip_bfloat16(st[(size_t)sizes[b * 64 + a0] * 32 + t]);
        rep[2336 + t] = __hip_bfloat16(st[(size_t)sizes[b * 64 + a1] * 32 + t]);
      }
    }
  }
  grid_bar(MEGA_BLOCKS);

  // ================= stage 3: GEMM layer 1 (768 units) =================
  {
    int u = blockIdx.x;
    int x = u & 7, y = (u >> 3) % 24, z = u / 192;
    gemm_stage(a.g1[z], x, y, smem);
  }
  grid_bar(MEGA_BLOCKS);

  // ================= stage 4: GEMM layer 2 (384 units) =================
  if (blockIdx.x < 384) {
    int u = blockIdx.x;
    int x = u & 7, y = (u >> 3) % 24, z = u / 192;
    gemm_stage(a.g2[z], x, y, smem);
  }
  grid_bar(MEGA_BLOCKS);

  // ================= stage 5: heads =================
  {
    int gr = blockIdx.x;
    const float* A; const float* W; const float* Bb; float* op; int N;
    if (gr < 128)      { A = a.NH  + (size_t)gr * HD;        W = a.nhw; Bb = a.nhb; N = 10; op = a.out + (size_t)gr * 10; }
    else if (gr < 384) { int r = gr - 128; A = a.RH2 + (size_t)r * HD; W = a.rw3; Bb = a.rb3; N = 8; op = a.out + 1280 + (size_t)r * 8; }
    else if (gr < 512) { int r = gr - 384; A = a.EH  + (size_t)r * HD; W = a.ehw; Bb = a.ehb; N = 2; op = a.out + 3328 + (size_t)r * 2; }
    else               { int r = gr - 512; A = a.CH2 + (size_t)r * HD; W = a.cw3; Bb = a.cb3; N = 1; op = a.out + 3584 + (size_t)r; }

    float acc[10];
    #pragma unroll
    for (int o = 0; o < 10; o++) acc[o] = 0.f;

    for (int k = t; k < HD; k += 256) {
      float av = A[k];
      #pragma unroll
      for (int o = 0; o < 10; o++) {
        int oo = (o < N) ? o : 0;
        acc[o] += av * W[(size_t)oo * HD + k];
      }
    }

    float* red = smem;   // [4][10]
    int lane = t & 63, wv = t >> 6;
    #pragma unroll
    for (int o = 0; o < 10; o++) {
      float v = acc[o];
      for (int off = 32; off > 0; off >>= 1) v += __shfl_down(v, off);
      if (lane == 0) red[wv * 10 + o] = v;
    }
    __syncthreads();
    if (t < N) {
      float v = red[0 * 10 + t] + red[1 * 10 + t] + red[2 * 10 + t] + red[3 * 10 + t] + Bb[t];
      op[t] = v;
    }
  }
}

// ---------------------------------------------------------------------------
extern "C" void kernel_launch(void* const* d_in, const int* in_sizes, int n_in,
                              void* d_out, int out_size, void* d_ws, size_t ws_size,
                              hipStream_t stream)
{
  const int*   input_ids  = (const int*)d_in[0];
  const int*   e_masks    = (const int*)d_in[1];
  const int*   e_sizes    = (const int*)d_in[2];
  const int*   m_masks    = (const int*)d_in[3];
  const int*   m_sizes    = (const int*)d_in[4];
  const int*   relations  = (const int*)d_in[5];
  const int*   r_masks    = (const int*)d_in[6];
  const int*   references = (const int*)d_in[7];
  const int*   c_masks    = (const int*)d_in[8];
  const float* emb        = (const float*)d_in[9];
  const float* nsemb      = (const float*)d_in[10];
  const float* esemb      = (const float*)d_in[11];
  const float* ner_rep_w  = (const float*)d_in[12];
  const float* ner_rep_b  = (const float*)d_in[13];
  const float* ner_head_w = (const float*)d_in[14];
  const float* ner_head_b = (const float*)d_in[15];
  const float* emd_rep_w  = (const float*)d_in[16];
  const float* emd_rep_b  = (const float*)d_in[17];
  const float* emd_head_w = (const float*)d_in[18];
  const float* emd_head_b = (const float*)d_in[19];
  const float* rel_w1 = (const float*)d_in[20];
  const float* rel_b1 = (const float*)d_in[21];
  const float* rel_w2 = (const float*)d_in[22];
  const float* rel_b2 = (const float*)d_in[23];
  const float* rel_w3 = (const float*)d_in[24];
  const float* rel_b3 = (const float*)d_in[25];
  const float* cr_w1 = (const float*)d_in[26];
  const float* cr_b1 = (const float*)d_in[27];
  const float* cr_w2 = (const float*)d_in[28];
  const float* cr_b2 = (const float*)d_in[29];
  const float* cr_w3 = (const float*)d_in[30];
  const float* cr_b3 = (const float*)d_in[31];
  float* out = (float*)d_out;

  // ---- workspace carve: f32/int region, then bf16 region ----
  float* wsf = (float*)d_ws;
  size_t o = 0;
  int*   FLAGS = (int*)(wsf + o); o += NSPLIT * 768;
  float* NH  = wsf + o; o += (size_t)128 * HD;
  float* EH  = wsf + o; o += (size_t)128 * HD;
  float* RH2 = wsf + o; o += (size_t)256 * HD;
  float* CH2 = wsf + o; o += (size_t)256 * HD;

  bf16* wsb = (bf16*)(wsf + o);
  size_t ob = 0;
  bf16* WBF   = wsb + ob; ob += (size_t)W_TOT;
  bf16* PART  = wsb + ob; ob += (size_t)NSPLIT * 768 * HD;
  bf16* EPOOL = wsb + ob; ob += (size_t)128 * HD;
  bf16* MPOOL = wsb + ob; ob += (size_t)128 * HD;
  bf16* RCTX  = wsb + ob; ob += (size_t)256 * HD;
  bf16* CCTX  = wsb + ob; ob += (size_t)256 * HD;
  bf16* NREP  = wsb + ob; ob += (size_t)128 * 1568;
  bf16* EREP  = wsb + ob; ob += (size_t)128 * 1568;
  bf16* RREP  = wsb + ob; ob += (size_t)256 * 2368;
  bf16* CREP  = wsb + ob; ob += (size_t)256 * 2368;
  bf16* RH1   = wsb + ob; ob += (size_t)256 * HD;
  bf16* CH1   = wsb + ob; ob += (size_t)256 * HD;

  // 1) fused weight-convert + pooling partials (1536 blocks, 6/CU)
  k_pool_cvt<<<POOL_BLOCKS, 256, 0, stream>>>(
      e_masks, m_masks, r_masks, c_masks, emb, PART, FLAGS,
      ner_rep_w, emd_rep_w, rel_w1, cr_w1, rel_w2, cr_w2, WBF);

  // 2) mega-kernel: combine -> rep -> gemm1 -> gemm2 -> heads
  MegaArgs ma;
  ma.part = PART; ma.flags = FLAGS;
  ma.epool = EPOOL; ma.mpool = MPOOL; ma.rctx = RCTX; ma.cctx = CCTX;
  ma.input_ids = input_ids; ma.emb = emb;
  ma.esizes = e_sizes; ma.msizes = m_sizes;
  ma.nsemb = nsemb; ma.esemb = esemb;
  ma.relations = relations; ma.references = references;
  ma.nrep = NREP; ma.erep = EREP; ma.rrep = RREP; ma.crep = CREP;
  ma.g1[0] = { NREP, WBF + WOFF_NER, ner_rep_b, NH,  1568, 128, 0 };
  ma.g1[1] = { EREP, WBF + WOFF_EMD, emd_rep_b, EH,  1568, 128, 0 };
  ma.g1[2] = { RREP, WBF + WOFF_RW1, rel_b1,    RH1, 2368, 256, 1 };
  ma.g1[3] = { CREP, WBF + WOFF_CW1, cr_b1,     CH1, 2368, 256, 1 };
  ma.g2[0] = { RH1, WBF + WOFF_RW2, rel_b2, RH2, 768, 256, 0 };
  ma.g2[1] = { CH1, WBF + WOFF_CW2, cr_b2,  CH2, 768, 256, 0 };
  ma.NH = NH; ma.EH = EH; ma.RH2 = RH2; ma.CH2 = CH2;
  ma.nhw = ner_head_w; ma.nhb = ner_head_b;
  ma.ehw = emd_head_w; ma.ehb = emd_head_b;
  ma.rw3 = rel_w3; ma.rb3 = rel_b3;
  ma.cw3 = cr_w3;  ma.cb3 = cr_b3;
  ma.out = out;

  k_mega<<<MEGA_BLOCKS, 256, 0, stream>>>(ma);
}

// Round 5
// 305.558 us; speedup vs baseline: 1.7206x; 1.7206x over previous
//
#include <hip/hip_runtime.h>
#include <hip/hip_bf16.h>

typedef __hip_bfloat16 bf16;
typedef __attribute__((ext_vector_type(8))) short short8;
typedef __attribute__((ext_vector_type(4))) float f32x4;

#define SS 512
#define HD 768
#define NEGC (-1e30f)
#define NSPLIT 16
#define TOK 32                 // SS / NSPLIT
#define POOL_BLOCKS 1536       // 48 groups * 2 batch * 16 splits

// bf16 weight blob offsets (elements)
#define WOFF_NER 0
#define WOFF_EMD 1204224
#define WOFF_RW1 2408448
#define WOFF_CW1 4227072
#define WOFF_RW2 6045696
#define WOFF_CW2 6635520
#define W_TOT    7225344
#define CVT_UNITS (W_TOT / 1024)   // 7056 units of 1024 elems

#define MEGA_BLOCKS 768

// ---------------------------------------------------------------------------
// Grid barrier. Arrival: sharded atomicAdd (8 padded counters, 96 arrivals
// each) -> root (8 arrivals) -> gen bump. Wait: pure LOAD spin on d_gen
// (no RMW in the spin loop — round-4's RMW spin serialized at L2 and cost
// ~85 us/barrier). Shard counters reset by shard-closer before root bump,
// root reset by releaser before gen bump => safe for graph replay.
// ---------------------------------------------------------------------------
__device__ unsigned d_shard[8 * 32] = {};
__device__ unsigned d_root = 0;
__device__ unsigned d_gen = 0;

__device__ __forceinline__ void grid_bar()
{
  __syncthreads();
  if (threadIdx.x == 0) {
    __threadfence();
    unsigned g = __hip_atomic_load(&d_gen, __ATOMIC_RELAXED, __HIP_MEMORY_SCOPE_AGENT);
    int sh = blockIdx.x & 7;
    unsigned prev = atomicAdd(&d_shard[sh * 32], 1u);
    if (prev == (MEGA_BLOCKS / 8) - 1) {          // last arrival in shard
      __hip_atomic_store(&d_shard[sh * 32], 0u, __ATOMIC_RELAXED, __HIP_MEMORY_SCOPE_AGENT);
      unsigned pr = atomicAdd(&d_root, 1u);
      if (pr == 7) {                              // last shard
        __hip_atomic_store(&d_root, 0u, __ATOMIC_RELAXED, __HIP_MEMORY_SCOPE_AGENT);
        __threadfence();
        atomicAdd(&d_gen, 1u);
      }
    }
    while (__hip_atomic_load(&d_gen, __ATOMIC_RELAXED, __HIP_MEMORY_SCOPE_AGENT) == g)
      __builtin_amdgcn_s_sleep(8);
    __threadfence();
  }
  __syncthreads();
}

// ---------------------------------------------------------------------------
// Dispatch 1: weight f32->bf16 convert (grid-stride prologue) + pooling.
// 1536 blocks x 256: 6 blocks/CU. Pool: 8 spans/block, 32 tokens (split sp
// of 16), all 768 h (3/thread). Partials bf16.
// ---------------------------------------------------------------------------
__global__ __launch_bounds__(256) void k_pool_cvt(
    const int* __restrict__ e_masks, const int* __restrict__ m_masks,
    const int* __restrict__ r_masks, const int* __restrict__ c_masks,
    const float* __restrict__ emb, bf16* __restrict__ part, int* __restrict__ flags,
    const float* __restrict__ s0, const float* __restrict__ s1,
    const float* __restrict__ s2, const float* __restrict__ s3,
    const float* __restrict__ s4, const float* __restrict__ s5,
    bf16* __restrict__ wdst)
{
  int bx = blockIdx.x;
  int t  = threadIdx.x;

  // ---- weight convert, grid-stride over 1024-elem units ----
  for (int u = bx; u < CVT_UNITS; u += POOL_BLOCKS) {
    size_t i = ((size_t)u * 256 + t) * 4;
    const float* s; size_t off;
    if      (i < WOFF_EMD) { s = s0; off = i; }
    else if (i < WOFF_RW1) { s = s1; off = i - WOFF_EMD; }
    else if (i < WOFF_CW1) { s = s2; off = i - WOFF_RW1; }
    else if (i < WOFF_RW2) { s = s3; off = i - WOFF_CW1; }
    else if (i < WOFF_CW2) { s = s4; off = i - WOFF_RW2; }
    else                   { s = s5; off = i - WOFF_CW2; }
    float4 v = *(const float4*)(s + off);
    wdst[i]     = __hip_bfloat16(v.x);
    wdst[i + 1] = __hip_bfloat16(v.y);
    wdst[i + 2] = __hip_bfloat16(v.z);
    wdst[i + 3] = __hip_bfloat16(v.w);
  }

  // ---- pooling ----
  int g  = bx % 48;              // span group (8 spans)
  int b  = (bx / 48) & 1;        // batch
  int sp = bx / 96;              // S-split 0..15 (32 tokens each)
  int j0 = g * 8;

  const int* marr; int row0;
  if      (j0 < 64)  { marr = e_masks; row0 = b*64  +  j0;        }
  else if (j0 < 128) { marr = m_masks; row0 = b*64  + (j0-64);    }
  else if (j0 < 256) { marr = r_masks; row0 = b*128 + (j0-128);   }
  else               { marr = c_masks; row0 = b*128 + (j0-256);   }

  __shared__ unsigned s_pack[TOK];
  __shared__ unsigned s_any;
  if (t == 0) s_any = 0u;
  __syncthreads();

  int sbase = sp * TOK;
  if (t < TOK) {
    unsigned w = 0;
    #pragma unroll
    for (int k = 0; k < 8; k++) {
      int mm = marr[(size_t)(row0 + k) * SS + sbase + t];
      w |= (mm != 0 ? 1u : 0u) << k;
    }
    s_pack[t] = w;
    atomicOr(&s_any, w);
  }
  __syncthreads();

  float acc[8][3];
  #pragma unroll
  for (int k = 0; k < 8; k++)
    #pragma unroll
    for (int i = 0; i < 3; i++) acc[k][i] = -INFINITY;

  const float* ebase = emb + ((size_t)b * SS + sbase) * HD;
  for (int s = 0; s < TOK; s++) {
    unsigned wm = s_pack[s];
    const float* ep = ebase + (size_t)s * HD + t;
    float v0 = ep[0];
    float v1 = ep[256];
    float v2 = ep[512];
    #pragma unroll
    for (int k = 0; k < 8; k++) {
      float add = ((wm >> k) & 1u) ? 0.f : NEGC;
      acc[k][0] = fmaxf(acc[k][0], v0 + add);
      acc[k][1] = fmaxf(acc[k][1], v1 + add);
      acc[k][2] = fmaxf(acc[k][2], v2 + add);
    }
  }

  #pragma unroll
  for (int k = 0; k < 8; k++) {
    int sg = b * 384 + j0 + k;
    bf16* dst = part + ((size_t)sp * 768 + sg) * HD;
    dst[t]       = __hip_bfloat16(acc[k][0]);
    dst[t + 256] = __hip_bfloat16(acc[k][1]);
    dst[t + 512] = __hip_bfloat16(acc[k][2]);
  }
  if (t < 8) flags[sp * 768 + b * 384 + j0 + t] = (int)((s_any >> t) & 1u);
}

// ---------------------------------------------------------------------------
// Mega-kernel plumbing
// ---------------------------------------------------------------------------
struct GemmArgs { const void* A; const void* W; const float* bias; void* C; int K; int M; int store_bf16; };

struct MegaArgs {
  const bf16* part; const int* flags;
  const int* input_ids; const float* emb;
  const int *esizes, *msizes;
  const float *nsemb, *esemb;
  const int *relations, *references;
  bf16 *nrep, *erep, *rrep, *crep;
  GemmArgs g1[4];
  GemmArgs g2[2];
  const float *NH, *EH, *RH2, *CH2;
  const float *nhw, *nhb, *ehw, *ehb, *rw3, *rb3, *cw3, *cb3;
  float* out;
};

// GEMM tile: C[32x32] = relu(A[Mt,K] @ W^T + bias). 4 waves split K, LDS-reduce.
__device__ __forceinline__ void gemm_stage(const GemmArgs& g, int x, int y, float* smem)
{
  int mt = x * 32;
  if (mt >= g.M) return;                 // block-uniform
  int nt = y * 32;
  const short* A = (const short*)g.A;
  const short* W = (const short*)g.W;
  int K_ = g.K;

  int wave = threadIdx.x >> 6, lane = threadIdx.x & 63;
  int lm = lane & 15, quad = lane >> 4;

  const short* a0p = A + (size_t)(mt + lm)      * K_ + quad * 8;
  const short* a1p = A + (size_t)(mt + 16 + lm) * K_ + quad * 8;
  const short* w0p = W + (size_t)(nt + lm)      * K_ + quad * 8;
  const short* w1p = W + (size_t)(nt + 16 + lm) * K_ + quad * 8;

  f32x4 acc00 = {0.f,0.f,0.f,0.f}, acc01 = {0.f,0.f,0.f,0.f};
  f32x4 acc10 = {0.f,0.f,0.f,0.f}, acc11 = {0.f,0.f,0.f,0.f};

  for (int k0 = wave * 32; k0 < K_; k0 += 128) {
    short8 a0 = *(const short8*)(a0p + k0);
    short8 a1 = *(const short8*)(a1p + k0);
    short8 w0 = *(const short8*)(w0p + k0);
    short8 w1 = *(const short8*)(w1p + k0);
    acc00 = __builtin_amdgcn_mfma_f32_16x16x32_bf16(a0, w0, acc00, 0, 0, 0);
    acc01 = __builtin_amdgcn_mfma_f32_16x16x32_bf16(a0, w1, acc01, 0, 0, 0);
    acc10 = __builtin_amdgcn_mfma_f32_16x16x32_bf16(a1, w0, acc10, 0, 0, 0);
    acc11 = __builtin_amdgcn_mfma_f32_16x16x32_bf16(a1, w1, acc11, 0, 0, 0);
  }

  // smem as [4][32][32]
  #pragma unroll
  for (int reg = 0; reg < 4; reg++) {
    int r = quad * 4 + reg;
    smem[wave*1024 + r*32 + lm]             = acc00[reg];
    smem[wave*1024 + r*32 + 16 + lm]        = acc01[reg];
    smem[wave*1024 + (16 + r)*32 + lm]      = acc10[reg];
    smem[wave*1024 + (16 + r)*32 + 16 + lm] = acc11[reg];
  }
  __syncthreads();

  int c = threadIdx.x & 31;
  int rb = threadIdx.x >> 5;
  float bb = g.bias[nt + c];
  #pragma unroll
  for (int i = 0; i < 4; i++) {
    int r = rb + 8 * i;
    float v = smem[r*32 + c] + smem[1024 + r*32 + c] + smem[2048 + r*32 + c] + smem[3072 + r*32 + c];
    v = fmaxf(v + bb, 0.f);
    if (g.store_bf16) ((bf16*)g.C)[(size_t)(mt + r) * HD + nt + c] = __hip_bfloat16(v);
    else              ((float*)g.C)[(size_t)(mt + r) * HD + nt + c] = v;
  }
  __syncthreads();   // protect smem before any reuse
}

// ---------------------------------------------------------------------------
// Mega-kernel: rep(from PART) -> gemm L1 -> gemm L2 -> heads; 3 grid barriers.
// 768 blocks x 256 thr; __launch_bounds__(256,3) => 3 blocks/CU co-resident.
// ---------------------------------------------------------------------------
__global__ __launch_bounds__(256, 3) void k_mega(MegaArgs a)
{
  __shared__ float smem[4 * 32 * 32];   // 16 KB, reused per stage
  __shared__ int s_cls;
  int t = threadIdx.x;

  // ========== stage 1: rep build (combine folded in; 768 units) ==========
  {
    int u = blockIdx.x;
    if (u < 256) {
      // span reps: [0,128) ner, [128,256) emd
      int which = u >> 7;
      int row = u & 127;                 // b*64 + e
      int b = row >> 6;
      int sg = b * 384 + (which ? 64 : 0) + (row & 63);
      const int*   sizes = which ? a.msizes : a.esizes;
      const float* st    = which ? a.esemb  : a.nsemb;
      bf16* rep = (which ? a.erep : a.nrep) + (size_t)row * 1568;

      if (t == 0) s_cls = SS;
      __syncthreads();
      for (int s = t; s < SS; s += 256)
        if (a.input_ids[b * SS + s] == 101) atomicMin(&s_cls, s);
      __syncthreads();
      int ci = (s_cls == SS) ? 0 : s_cls;
      const float* ctx = a.emb + ((size_t)b * SS + ci) * HD;

      for (int h = t; h < HD; h += 256) {
        float v = -INFINITY;
        #pragma unroll
        for (int sp = 0; sp < NSPLIT; sp++)
          v = fmaxf(v, (float)a.part[((size_t)sp * 768 + sg) * HD + h]);
        rep[h]       = __hip_bfloat16(ctx[h]);
        rep[768 + h] = __hip_bfloat16(v);
      }
      if (t < 32)
        rep[1536 + t] = __hip_bfloat16(st[(size_t)sizes[row] * 32 + t]);
    } else {
      // relation reps: [256,512) rel, [512,768) cr
      int v2 = u - 256;
      int which = v2 >> 8;
      int row = v2 & 255;                // b*128 + r
      int b = row >> 7;
      int sgc = b * 384 + (which ? 256 : 128) + (row & 127);
      const int*   rel   = which ? a.references : a.relations;
      const int*   sizes = which ? a.msizes : a.esizes;
      const float* st    = which ? a.esemb  : a.nsemb;
      bf16* rep = (which ? a.crep : a.rrep) + (size_t)row * 2368;

      int a0 = rel[row * 2], a1 = rel[row * 2 + 1];
      int sg0 = b * 384 + (which ? 64 : 0) + a0;
      int sg1 = b * 384 + (which ? 64 : 0) + a1;
      int any = 0;
      #pragma unroll
      for (int sp = 0; sp < NSPLIT; sp++) any |= a.flags[sp * 768 + sgc];

      for (int h = t; h < HD; h += 256) {
        float vc = -INFINITY, p0 = -INFINITY, p1 = -INFINITY;
        #pragma unroll
        for (int sp = 0; sp < NSPLIT; sp++) {
          vc = fmaxf(vc, (float)a.part[((size_t)sp * 768 + sgc) * HD + h]);
          p0 = fmaxf(p0, (float)a.part[((size_t)sp * 768 + sg0) * HD + h]);
          p1 = fmaxf(p1, (float)a.part[((size_t)sp * 768 + sg1) * HD + h]);
        }
        rep[h]        = __hip_bfloat16(any ? vc : 0.f);
        rep[768 + h]  = __hip_bfloat16(p0);
        rep[1536 + h] = __hip_bfloat16(p1);
      }
      if (t < 32) {
        rep[2304 + t] = __hip_bfloat16(st[(size_t)sizes[b * 64 + a0] * 32 + t]);
        rep[2336 + t] = __hip_bfloat16(st[(size_t)sizes[b * 64 + a1] * 32 + t]);
      }
    }
  }
  grid_bar();

  // ========== stage 2: GEMM layer 1 (768 units) ==========
  {
    int u = blockIdx.x;
    int x = u & 7, y = (u >> 3) % 24, z = u / 192;
    gemm_stage(a.g1[z], x, y, smem);
  }
  grid_bar();

  // ========== stage 3: GEMM layer 2 (384 units) ==========
  if (blockIdx.x < 384) {
    int u = blockIdx.x;
    int x = u & 7, y = (u >> 3) % 24, z = u / 192;
    gemm_stage(a.g2[z], x, y, smem);
  }
  grid_bar();

  // ========== stage 4: heads ==========
  {
    int gr = blockIdx.x;
    const float* A; const float* W; const float* Bb; float* op; int N;
    if (gr < 128)      { A = a.NH  + (size_t)gr * HD;        W = a.nhw; Bb = a.nhb; N = 10; op = a.out + (size_t)gr * 10; }
    else if (gr < 384) { int r = gr - 128; A = a.RH2 + (size_t)r * HD; W = a.rw3; Bb = a.rb3; N = 8; op = a.out + 1280 + (size_t)r * 8; }
    else if (gr < 512) { int r = gr - 384; A = a.EH  + (size_t)r * HD; W = a.ehw; Bb = a.ehb; N = 2; op = a.out + 3328 + (size_t)r * 2; }
    else               { int r = gr - 512; A = a.CH2 + (size_t)r * HD; W = a.cw3; Bb = a.cb3; N = 1; op = a.out + 3584 + (size_t)r; }

    float acc[10];
    #pragma unroll
    for (int o = 0; o < 10; o++) acc[o] = 0.f;

    for (int k = t; k < HD; k += 256) {
      float av = A[k];
      #pragma unroll
      for (int o = 0; o < 10; o++) {
        int oo = (o < N) ? o : 0;
        acc[o] += av * W[(size_t)oo * HD + k];
      }
    }

    float* red = smem;   // [4][10]
    int lane = t & 63, wv = t >> 6;
    #pragma unroll
    for (int o = 0; o < 10; o++) {
      float v = acc[o];
      for (int off = 32; off > 0; off >>= 1) v += __shfl_down(v, off);
      if (lane == 0) red[wv * 10 + o] = v;
    }
    __syncthreads();
    if (t < N) {
      float v = red[0 * 10 + t] + red[1 * 10 + t] + red[2 * 10 + t] + red[3 * 10 + t] + Bb[t];
      op[t] = v;
    }
  }
}

// ---------------------------------------------------------------------------
extern "C" void kernel_launch(void* const* d_in, const int* in_sizes, int n_in,
                              void* d_out, int out_size, void* d_ws, size_t ws_size,
                              hipStream_t stream)
{
  const int*   input_ids  = (const int*)d_in[0];
  const int*   e_masks    = (const int*)d_in[1];
  const int*   e_sizes    = (const int*)d_in[2];
  const int*   m_masks    = (const int*)d_in[3];
  const int*   m_sizes    = (const int*)d_in[4];
  const int*   relations  = (const int*)d_in[5];
  const int*   r_masks    = (const int*)d_in[6];
  const int*   references = (const int*)d_in[7];
  const int*   c_masks    = (const int*)d_in[8];
  const float* emb        = (const float*)d_in[9];
  const float* nsemb      = (const float*)d_in[10];
  const float* esemb      = (const float*)d_in[11];
  const float* ner_rep_w  = (const float*)d_in[12];
  const float* ner_rep_b  = (const float*)d_in[13];
  const float* ner_head_w = (const float*)d_in[14];
  const float* ner_head_b = (const float*)d_in[15];
  const float* emd_rep_w  = (const float*)d_in[16];
  const float* emd_rep_b  = (const float*)d_in[17];
  const float* emd_head_w = (const float*)d_in[18];
  const float* emd_head_b = (const float*)d_in[19];
  const float* rel_w1 = (const float*)d_in[20];
  const float* rel_b1 = (const float*)d_in[21];
  const float* rel_w2 = (const float*)d_in[22];
  const float* rel_b2 = (const float*)d_in[23];
  const float* rel_w3 = (const float*)d_in[24];
  const float* rel_b3 = (const float*)d_in[25];
  const float* cr_w1 = (const float*)d_in[26];
  const float* cr_b1 = (const float*)d_in[27];
  const float* cr_w2 = (const float*)d_in[28];
  const float* cr_b2 = (const float*)d_in[29];
  const float* cr_w3 = (const float*)d_in[30];
  const float* cr_b3 = (const float*)d_in[31];
  float* out = (float*)d_out;

  // ---- workspace carve: f32/int region, then bf16 region ----
  float* wsf = (float*)d_ws;
  size_t o = 0;
  int*   FLAGS = (int*)(wsf + o); o += NSPLIT * 768;
  float* NH  = wsf + o; o += (size_t)128 * HD;
  float* EH  = wsf + o; o += (size_t)128 * HD;
  float* RH2 = wsf + o; o += (size_t)256 * HD;
  float* CH2 = wsf + o; o += (size_t)256 * HD;

  bf16* wsb = (bf16*)(wsf + o);
  size_t ob = 0;
  bf16* WBF   = wsb + ob; ob += (size_t)W_TOT;
  bf16* PART  = wsb + ob; ob += (size_t)NSPLIT * 768 * HD;
  bf16* NREP  = wsb + ob; ob += (size_t)128 * 1568;
  bf16* EREP  = wsb + ob; ob += (size_t)128 * 1568;
  bf16* RREP  = wsb + ob; ob += (size_t)256 * 2368;
  bf16* CREP  = wsb + ob; ob += (size_t)256 * 2368;
  bf16* RH1   = wsb + ob; ob += (size_t)256 * HD;
  bf16* CH1   = wsb + ob; ob += (size_t)256 * HD;

  // 1) fused weight-convert + pooling partials (1536 blocks, 6/CU)
  k_pool_cvt<<<POOL_BLOCKS, 256, 0, stream>>>(
      e_masks, m_masks, r_masks, c_masks, emb, PART, FLAGS,
      ner_rep_w, emd_rep_w, rel_w1, cr_w1, rel_w2, cr_w2, WBF);

  // 2) mega-kernel: rep -> gemm1 -> gemm2 -> heads
  MegaArgs ma;
  ma.part = PART; ma.flags = FLAGS;
  ma.input_ids = input_ids; ma.emb = emb;
  ma.esizes = e_sizes; ma.msizes = m_sizes;
  ma.nsemb = nsemb; ma.esemb = esemb;
  ma.relations = relations; ma.references = references;
  ma.nrep = NREP; ma.erep = EREP; ma.rrep = RREP; ma.crep = CREP;
  ma.g1[0] = { NREP, WBF + WOFF_NER, ner_rep_b, NH,  1568, 128, 0 };
  ma.g1[1] = { EREP, WBF + WOFF_EMD, emd_rep_b, EH,  1568, 128, 0 };
  ma.g1[2] = { RREP, WBF + WOFF_RW1, rel_b1,    RH1, 2368, 256, 1 };
  ma.g1[3] = { CREP, WBF + WOFF_CW1, cr_b1,     CH1, 2368, 256, 1 };
  ma.g2[0] = { RH1, WBF + WOFF_RW2, rel_b2, RH2, 768, 256, 0 };
  ma.g2[1] = { CH1, WBF + WOFF_CW2, cr_b2,  CH2, 768, 256, 0 };
  ma.NH = NH; ma.EH = EH; ma.RH2 = RH2; ma.CH2 = CH2;
  ma.nhw = ner_head_w; ma.nhb = ner_head_b;
  ma.ehw = emd_head_w; ma.ehb = emd_head_b;
  ma.rw3 = rel_w3; ma.rb3 = rel_b3;
  ma.cw3 = cr_w3;  ma.cb3 = cr_b3;
  ma.out = out;

  k_mega<<<MEGA_BLOCKS, 256, 0, stream>>>(ma);
}

// Round 6
// 254.423 us; speedup vs baseline: 2.0664x; 1.2010x over previous
//
#include <hip/hip_runtime.h>
#include <hip/hip_bf16.h>

typedef __hip_bfloat16 bf16;
typedef __attribute__((ext_vector_type(8))) short short8;
typedef __attribute__((ext_vector_type(4))) float f32x4;

#define SS 512
#define HD 768
#define NEGC (-1e30f)

// bf16 weight blob offsets (elements)
#define WOFF_NER 0
#define WOFF_EMD 1204224
#define WOFF_RW1 2408448
#define WOFF_CW1 4227072
#define WOFF_RW2 6045696
#define WOFF_CW2 6635520
#define W_TOT    7225344
#define PC_BLOCKS 576              // 48 groups x 2 batch x 6 h-chunks
#define CVT_UNITS (W_TOT / 1024)   // 7056

// ---------------------------------------------------------------------------
// Dispatch 1: weight f32->bf16 convert (grid-stride) + DIRECT pooling.
// Grid (48,2,6), block 256 = (hl in [0,128), sh in {0,1}).
// Each thread: 4 spans x 1 h, full 512-token reduction -> final pools/ctx.
// No PART buffer, no combine stage. z==5 blocks also build size-emb tables,
// bf16 ctx rows, and zero d_out (for the head atomics).
// ---------------------------------------------------------------------------
__global__ __launch_bounds__(256) void k_pool_cvt(
    const int* __restrict__ e_masks, const int* __restrict__ m_masks,
    const int* __restrict__ r_masks, const int* __restrict__ c_masks,
    const float* __restrict__ emb, const int* __restrict__ input_ids,
    const int* __restrict__ esizes, const int* __restrict__ msizes,
    const float* __restrict__ nsemb, const float* __restrict__ esemb,
    const float* __restrict__ s0, const float* __restrict__ s1,
    const float* __restrict__ s2, const float* __restrict__ s3,
    const float* __restrict__ s4, const float* __restrict__ s5,
    bf16* __restrict__ wdst,
    bf16* __restrict__ epool, bf16* __restrict__ mpool,
    bf16* __restrict__ rctx, bf16* __restrict__ cctx,
    bf16* __restrict__ sze, bf16* __restrict__ szm,
    bf16* __restrict__ ctxb, float* __restrict__ out)
{
  int t  = threadIdx.x;
  int g  = blockIdx.x;               // span group (8 spans)
  int b  = blockIdx.y;               // batch
  int hc = blockIdx.z;               // h-chunk 0..5

  // ---- weight convert, grid-stride over 1024-elem units ----
  int bx = g + 48 * b + 96 * hc;
  for (int u = bx; u < CVT_UNITS; u += PC_BLOCKS) {
    size_t i = ((size_t)u * 256 + t) * 4;
    const float* s; size_t off;
    if      (i < WOFF_EMD) { s = s0; off = i; }
    else if (i < WOFF_RW1) { s = s1; off = i - WOFF_EMD; }
    else if (i < WOFF_CW1) { s = s2; off = i - WOFF_RW1; }
    else if (i < WOFF_RW2) { s = s3; off = i - WOFF_CW1; }
    else if (i < WOFF_CW2) { s = s4; off = i - WOFF_RW2; }
    else                   { s = s5; off = i - WOFF_CW2; }
    float4 v = *(const float4*)(s + off);
    wdst[i]     = __hip_bfloat16(v.x);
    wdst[i + 1] = __hip_bfloat16(v.y);
    wdst[i + 2] = __hip_bfloat16(v.z);
    wdst[i + 3] = __hip_bfloat16(v.w);
  }

  // ---- mask staging: 8 bits per token ----
  int j0 = g * 8;
  const int* marr; int row0;
  if      (j0 < 64)  { marr = e_masks; row0 = b*64  +  j0;        }
  else if (j0 < 128) { marr = m_masks; row0 = b*64  + (j0-64);    }
  else if (j0 < 256) { marr = r_masks; row0 = b*128 + (j0-128);   }
  else               { marr = c_masks; row0 = b*128 + (j0-256);   }

  __shared__ unsigned s_pack[SS];
  __shared__ unsigned s_any;
  __shared__ int s_cls;
  if (t == 0) { s_any = 0u; s_cls = SS; }
  __syncthreads();

  unsigned wor = 0;
  for (int s = t; s < SS; s += 256) {
    unsigned w = 0;
    #pragma unroll
    for (int k = 0; k < 8; k++) {
      int mm = marr[(size_t)(row0 + k) * SS + s];
      w |= (mm != 0 ? 1u : 0u) << k;
    }
    s_pack[s] = w;
    wor |= w;
  }
  atomicOr(&s_any, wor);
  __syncthreads();

  // ---- full-token max reduction: 4 spans x 1 h per thread ----
  int hl = t & 127, sh = t >> 7;
  int h = hc * 128 + hl;
  const float* ep = emb + (size_t)b * SS * HD + h;
  float a0 = -INFINITY, a1 = -INFINITY, a2 = -INFINITY, a3 = -INFINITY;
  #pragma unroll 4
  for (int s = 0; s < SS; s++) {
    float v = ep[(size_t)s * HD];
    unsigned wm = s_pack[s] >> (sh * 4);
    a0 = (wm & 1u) ? fmaxf(a0, v) : a0;
    a1 = (wm & 2u) ? fmaxf(a1, v) : a1;
    a2 = (wm & 4u) ? fmaxf(a2, v) : a2;
    a3 = (wm & 8u) ? fmaxf(a3, v) : a3;
  }

  unsigned anyw = s_any;
  float acc[4] = { a0, a1, a2, a3 };
  #pragma unroll
  for (int kk = 0; kk < 4; kk++) {
    int kbit = sh * 4 + kk;
    int j = j0 + kbit;
    float v = acc[kk];
    int any = (anyw >> kbit) & 1u;
    if      (j < 64)  epool[((size_t)b*64  + j)       * HD + h] = __hip_bfloat16(v);
    else if (j < 128) mpool[((size_t)b*64  + (j-64))  * HD + h] = __hip_bfloat16(v);
    else if (j < 256) rctx [((size_t)b*128 + (j-128)) * HD + h] = __hip_bfloat16(any ? v : 0.f);
    else              cctx [((size_t)b*128 + (j-256)) * HD + h] = __hip_bfloat16(any ? v : 0.f);
  }

  // ---- auxiliary tasks on z==5 ----
  if (hc == 5) {
    if (g == 0) {                      // entity size-emb table (rows b*64..)
      for (int i = t; i < 64 * 32; i += 256) {
        int r = b * 64 + (i >> 5), c = i & 31;
        sze[(size_t)r * 32 + c] = __hip_bfloat16(nsemb[(size_t)esizes[r] * 32 + c]);
      }
    } else if (g == 1) {               // mention size-emb table
      for (int i = t; i < 64 * 32; i += 256) {
        int r = b * 64 + (i >> 5), c = i & 31;
        szm[(size_t)r * 32 + c] = __hip_bfloat16(esemb[(size_t)msizes[r] * 32 + c]);
      }
    } else if (g == 2) {               // bf16 cls-ctx row for batch b
      for (int s = t; s < SS; s += 256)
        if (input_ids[b * SS + s] == 101) atomicMin(&s_cls, s);
      __syncthreads();
      int ci = (s_cls == SS) ? 0 : s_cls;
      for (int hh = t; hh < HD; hh += 256)
        ctxb[(size_t)b * HD + hh] = __hip_bfloat16(emb[((size_t)b * SS + ci) * HD + hh]);
    } else if (g == 3) {               // zero d_out (3840 floats, 2 blocks)
      for (int i = t; i < 1920; i += 256) out[b * 1920 + i] = 0.f;
    }
  }
}

// ---------------------------------------------------------------------------
// GEMM layer 1 with on-the-fly A gather. All rep segment boundaries
// (768/1536/2304/2336) are multiples of 32 == the MFMA K-chunk, so each
// K-iteration's 32-wide chunk lies in exactly one segment.
// grid (8, 24, 4-problems), block 256 = 4 waves K-split, LDS reduce.
// Span problems (z<2): head fused via f32 atomicAdd. Rel (z>=2): store RH1/CH1.
// ---------------------------------------------------------------------------
struct P1 {
  const bf16 *ctx, *pool, *sz; const int* ridx;
  const short* W; const float* bias;
  bf16* C;                 // null for span problems
  const float *hw, *hb; float* outp;
  int is_rel, N, K, Mtiles;
};
struct P1x4 { P1 p[4]; };

__global__ __launch_bounds__(256, 2) void k_gemm1(P1x4 args)
{
  P1 g = args.p[blockIdx.z];
  int x = blockIdx.x;
  if (x >= g.Mtiles) return;
  int mt = x * 32, nt = blockIdx.y * 32;
  int wave = threadIdx.x >> 6, lane = threadIdx.x & 63;
  int lm = lane & 15, quad = lane >> 4;
  int K_ = g.K;

  // per-row segment base pointers
  const bf16 *g0[2], *g1[2], *g2[2], *g3[2], *g4[2];
  int rr[2] = { mt + lm, mt + 16 + lm };
  #pragma unroll
  for (int i = 0; i < 2; i++) {
    int r = rr[i];
    if (g.is_rel) {
      int b = r >> 7;
      int i0 = g.ridx[2 * r], i1 = g.ridx[2 * r + 1];
      g0[i] = g.ctx  + (size_t)r * HD;
      g1[i] = g.pool + (size_t)(b * 64 + i0) * HD;
      g2[i] = g.pool + (size_t)(b * 64 + i1) * HD;
      g3[i] = g.sz   + (size_t)(b * 64 + i0) * 32;
      g4[i] = g.sz   + (size_t)(b * 64 + i1) * 32;
    } else {
      g0[i] = g.ctx  + (size_t)(r >> 6) * HD;
      g1[i] = g.pool + (size_t)r * HD;
      g2[i] = g.sz   + (size_t)r * 32;
      g3[i] = g2[i]; g4[i] = g2[i];
    }
  }
  const short* w0p = g.W + (size_t)(nt + lm)      * K_ + quad * 8;
  const short* w1p = g.W + (size_t)(nt + 16 + lm) * K_ + quad * 8;

  f32x4 acc00 = {0.f,0.f,0.f,0.f}, acc01 = {0.f,0.f,0.f,0.f};
  f32x4 acc10 = {0.f,0.f,0.f,0.f}, acc11 = {0.f,0.f,0.f,0.f};

  for (int k32 = wave * 32; k32 < K_; k32 += 128) {
    const bf16 *b0, *b1;
    if      (k32 < 768)  { b0 = g0[0] + k32;          b1 = g0[1] + k32;          }
    else if (k32 < 1536) { b0 = g1[0] + (k32 - 768);  b1 = g1[1] + (k32 - 768);  }
    else if (k32 < 2304) { b0 = g2[0] + (k32 - 1536); b1 = g2[1] + (k32 - 1536); }
    else if (k32 < 2336) { b0 = g3[0] + (k32 - 2304); b1 = g3[1] + (k32 - 2304); }
    else                 { b0 = g4[0] + (k32 - 2336); b1 = g4[1] + (k32 - 2336); }
    short8 a0 = *(const short8*)((const short*)b0 + quad * 8);
    short8 a1 = *(const short8*)((const short*)b1 + quad * 8);
    short8 w0 = *(const short8*)(w0p + k32);
    short8 w1 = *(const short8*)(w1p + k32);
    acc00 = __builtin_amdgcn_mfma_f32_16x16x32_bf16(a0, w0, acc00, 0, 0, 0);
    acc01 = __builtin_amdgcn_mfma_f32_16x16x32_bf16(a0, w1, acc01, 0, 0, 0);
    acc10 = __builtin_amdgcn_mfma_f32_16x16x32_bf16(a1, w0, acc10, 0, 0, 0);
    acc11 = __builtin_amdgcn_mfma_f32_16x16x32_bf16(a1, w1, acc11, 0, 0, 0);
  }

  __shared__ float smem[4 * 32 * 32];
  #pragma unroll
  for (int reg = 0; reg < 4; reg++) {
    int r = quad * 4 + reg;
    smem[wave*1024 + r*32 + lm]             = acc00[reg];
    smem[wave*1024 + r*32 + 16 + lm]        = acc01[reg];
    smem[wave*1024 + (16 + r)*32 + lm]      = acc10[reg];
    smem[wave*1024 + (16 + r)*32 + 16 + lm] = acc11[reg];
  }
  __syncthreads();

  int c = threadIdx.x & 31;
  int rb = threadIdx.x >> 5;
  float bb = g.bias[nt + c];
  #pragma unroll
  for (int i = 0; i < 4; i++) {
    int r = rb + 8 * i;
    float v = smem[r*32 + c] + smem[1024 + r*32 + c] + smem[2048 + r*32 + c] + smem[3072 + r*32 + c];
    v = fmaxf(v + bb, 0.f);
    if (g.C) g.C[(size_t)(mt + r) * HD + nt + c] = __hip_bfloat16(v);
    else     smem[r*32 + c] = v;        // (r,c) owner-exclusive slot
  }
  __syncthreads();

  if (!g.C) {   // fused span head: out[row][o] += H[r][:] . hw[o][nt:nt+32]
    int r = threadIdx.x >> 3, oi = threadIdx.x & 7;
    for (int o = oi; o < g.N; o += 8) {
      float s = 0.f;
      #pragma unroll
      for (int cc = 0; cc < 32; cc++) {
        int c2 = (cc + r) & 31;         // rotate: bank-conflict-free
        s += smem[r*32 + c2] * g.hw[(size_t)o * HD + nt + c2];
      }
      if (blockIdx.y == 0) s += g.hb[o];
      atomicAdd(g.outp + (size_t)(mt + r) * g.N + o, s);
    }
  }
}

// ---------------------------------------------------------------------------
// GEMM layer 2 (contiguous A) + fused rel/cr heads. grid (8,24,2), block 256.
// ---------------------------------------------------------------------------
struct P2 { const short* A; const short* W; const float* bias;
            const float *hw, *hb; float* outp; int N; };
struct P2x2 { P2 p[2]; };

__global__ __launch_bounds__(256, 2) void k_gemm2(P2x2 args)
{
  P2 g = args.p[blockIdx.z];
  int mt = blockIdx.x * 32, nt = blockIdx.y * 32;
  int wave = threadIdx.x >> 6, lane = threadIdx.x & 63;
  int lm = lane & 15, quad = lane >> 4;

  const short* a0p = g.A + (size_t)(mt + lm)      * HD + quad * 8;
  const short* a1p = g.A + (size_t)(mt + 16 + lm) * HD + quad * 8;
  const short* w0p = g.W + (size_t)(nt + lm)      * HD + quad * 8;
  const short* w1p = g.W + (size_t)(nt + 16 + lm) * HD + quad * 8;

  f32x4 acc00 = {0.f,0.f,0.f,0.f}, acc01 = {0.f,0.f,0.f,0.f};
  f32x4 acc10 = {0.f,0.f,0.f,0.f}, acc11 = {0.f,0.f,0.f,0.f};

  for (int k32 = wave * 32; k32 < HD; k32 += 128) {
    short8 a0 = *(const short8*)(a0p + k32);
    short8 a1 = *(const short8*)(a1p + k32);
    short8 w0 = *(const short8*)(w0p + k32);
    short8 w1 = *(const short8*)(w1p + k32);
    acc00 = __builtin_amdgcn_mfma_f32_16x16x32_bf16(a0, w0, acc00, 0, 0, 0);
    acc01 = __builtin_amdgcn_mfma_f32_16x16x32_bf16(a0, w1, acc01, 0, 0, 0);
    acc10 = __builtin_amdgcn_mfma_f32_16x16x32_bf16(a1, w0, acc10, 0, 0, 0);
    acc11 = __builtin_amdgcn_mfma_f32_16x16x32_bf16(a1, w1, acc11, 0, 0, 0);
  }

  __shared__ float smem[4 * 32 * 32];
  #pragma unroll
  for (int reg = 0; reg < 4; reg++) {
    int r = quad * 4 + reg;
    smem[wave*1024 + r*32 + lm]             = acc00[reg];
    smem[wave*1024 + r*32 + 16 + lm]        = acc01[reg];
    smem[wave*1024 + (16 + r)*32 + lm]      = acc10[reg];
    smem[wave*1024 + (16 + r)*32 + 16 + lm] = acc11[reg];
  }
  __syncthreads();

  int c = threadIdx.x & 31;
  int rb = threadIdx.x >> 5;
  float bb = g.bias[nt + c];
  #pragma unroll
  for (int i = 0; i < 4; i++) {
    int r = rb + 8 * i;
    float v = smem[r*32 + c] + smem[1024 + r*32 + c] + smem[2048 + r*32 + c] + smem[3072 + r*32 + c];
    smem[r*32 + c] = fmaxf(v + bb, 0.f);
  }
  __syncthreads();

  int r = threadIdx.x >> 3, oi = threadIdx.x & 7;
  for (int o = oi; o < g.N; o += 8) {
    float s = 0.f;
    #pragma unroll
    for (int cc = 0; cc < 32; cc++) {
      int c2 = (cc + r) & 31;
      s += smem[r*32 + c2] * g.hw[(size_t)o * HD + nt + c2];
    }
    if (blockIdx.y == 0) s += g.hb[o];
    atomicAdd(g.outp + (size_t)(mt + r) * g.N + o, s);
  }
}

// ---------------------------------------------------------------------------
extern "C" void kernel_launch(void* const* d_in, const int* in_sizes, int n_in,
                              void* d_out, int out_size, void* d_ws, size_t ws_size,
                              hipStream_t stream)
{
  const int*   input_ids  = (const int*)d_in[0];
  const int*   e_masks    = (const int*)d_in[1];
  const int*   e_sizes    = (const int*)d_in[2];
  const int*   m_masks    = (const int*)d_in[3];
  const int*   m_sizes    = (const int*)d_in[4];
  const int*   relations  = (const int*)d_in[5];
  const int*   r_masks    = (const int*)d_in[6];
  const int*   references = (const int*)d_in[7];
  const int*   c_masks    = (const int*)d_in[8];
  const float* emb        = (const float*)d_in[9];
  const float* nsemb      = (const float*)d_in[10];
  const float* esemb      = (const float*)d_in[11];
  const float* ner_rep_w  = (const float*)d_in[12];
  const float* ner_rep_b  = (const float*)d_in[13];
  const float* ner_head_w = (const float*)d_in[14];
  const float* ner_head_b = (const float*)d_in[15];
  const float* emd_rep_w  = (const float*)d_in[16];
  const float* emd_rep_b  = (const float*)d_in[17];
  const float* emd_head_w = (const float*)d_in[18];
  const float* emd_head_b = (const float*)d_in[19];
  const float* rel_w1 = (const float*)d_in[20];
  const float* rel_b1 = (const float*)d_in[21];
  const float* rel_w2 = (const float*)d_in[22];
  const float* rel_b2 = (const float*)d_in[23];
  const float* rel_w3 = (const float*)d_in[24];
  const float* rel_b3 = (const float*)d_in[25];
  const float* cr_w1 = (const float*)d_in[26];
  const float* cr_b1 = (const float*)d_in[27];
  const float* cr_w2 = (const float*)d_in[28];
  const float* cr_b2 = (const float*)d_in[29];
  const float* cr_w3 = (const float*)d_in[30];
  const float* cr_b3 = (const float*)d_in[31];
  float* out = (float*)d_out;

  // ---- workspace carve (all bf16) ----
  bf16* wsb = (bf16*)d_ws;
  size_t ob = 0;
  bf16* WBF   = wsb + ob; ob += (size_t)W_TOT;
  bf16* EPOOL = wsb + ob; ob += (size_t)128 * HD;
  bf16* MPOOL = wsb + ob; ob += (size_t)128 * HD;
  bf16* RCTX  = wsb + ob; ob += (size_t)256 * HD;
  bf16* CCTX  = wsb + ob; ob += (size_t)256 * HD;
  bf16* SZE   = wsb + ob; ob += (size_t)128 * 32;
  bf16* SZM   = wsb + ob; ob += (size_t)128 * 32;
  bf16* CTXB  = wsb + ob; ob += (size_t)2 * HD;
  bf16* RH1   = wsb + ob; ob += (size_t)256 * HD;
  bf16* CH1   = wsb + ob; ob += (size_t)256 * HD;

  // 1) convert + direct pooling + aux tables + d_out zero
  k_pool_cvt<<<dim3(48, 2, 6), 256, 0, stream>>>(
      e_masks, m_masks, r_masks, c_masks, emb, input_ids,
      e_sizes, m_sizes, nsemb, esemb,
      ner_rep_w, emd_rep_w, rel_w1, cr_w1, rel_w2, cr_w2, WBF,
      EPOOL, MPOOL, RCTX, CCTX, SZE, SZM, CTXB, out);

  // 2) GEMM layer 1 (gathered A) + fused span heads
  P1x4 a1;
  a1.p[0] = { CTXB, EPOOL, SZE, nullptr,    (const short*)(WBF + WOFF_NER), ner_rep_b,
              nullptr, ner_head_w, ner_head_b, out,        0, 10, 1568, 4 };
  a1.p[1] = { CTXB, MPOOL, SZM, nullptr,    (const short*)(WBF + WOFF_EMD), emd_rep_b,
              nullptr, emd_head_w, emd_head_b, out + 3328, 0, 2,  1568, 4 };
  a1.p[2] = { RCTX, EPOOL, SZE, relations,  (const short*)(WBF + WOFF_RW1), rel_b1,
              RH1, nullptr, nullptr, nullptr,              1, 0,  2368, 8 };
  a1.p[3] = { CCTX, MPOOL, SZM, references, (const short*)(WBF + WOFF_CW1), cr_b1,
              CH1, nullptr, nullptr, nullptr,              1, 0,  2368, 8 };
  k_gemm1<<<dim3(8, 24, 4), 256, 0, stream>>>(a1);

  // 3) GEMM layer 2 + fused rel/cr heads
  P2x2 a2;
  a2.p[0] = { (const short*)RH1, (const short*)(WBF + WOFF_RW2), rel_b2,
              rel_w3, rel_b3, out + 1280, 8 };
  a2.p[1] = { (const short*)CH1, (const short*)(WBF + WOFF_CW2), cr_b2,
              cr_w3, cr_b3, out + 3584, 1 };
  k_gemm2<<<dim3(8, 24, 2), 256, 0, stream>>>(a2);
}

// Round 7
// 220.920 us; speedup vs baseline: 2.3798x; 1.1516x over previous
//
#include <hip/hip_runtime.h>
#include <hip/hip_bf16.h>

typedef __hip_bfloat16 bf16;
typedef __attribute__((ext_vector_type(8))) short short8;
typedef __attribute__((ext_vector_type(4))) float f32x4;

#define SS 512
#define HD 768
#define NSPLIT 8

// bf16 weight blob offsets (elements)
#define WOFF_NER 0
#define WOFF_EMD 1204224
#define WOFF_RW1 2408448
#define WOFF_CW1 4227072
#define WOFF_RW2 6045696
#define WOFF_CW2 6635520
#define W_TOT    7225344
#define CVT_BLOCKS (W_TOT / 4096)      // 1764 (all segment bounds % 4096 == 0)
#define D1_BLOCKS (768 + CVT_BLOCKS + 4)

// ---------------------------------------------------------------------------
// Dispatch 1: pool partials (bx<768) | weight cvt (768..768+1764) | aux (last 4).
// Pool: 8 spans, 64 tokens (split sp of 8), 768 h (3/thread). Mask bits are
// block-uniform -> readfirstlane + scalar branch: only ~50% of (span,token)
// pairs execute the 3 v_max ops. Partials bf16 (max commutes with rounding).
// ---------------------------------------------------------------------------
__global__ __launch_bounds__(256) void k_d1(
    const int* __restrict__ e_masks, const int* __restrict__ m_masks,
    const int* __restrict__ r_masks, const int* __restrict__ c_masks,
    const float* __restrict__ emb, const int* __restrict__ input_ids,
    const int* __restrict__ esizes, const int* __restrict__ msizes,
    const float* __restrict__ nsemb, const float* __restrict__ esemb,
    const float* __restrict__ s0, const float* __restrict__ s1,
    const float* __restrict__ s2, const float* __restrict__ s3,
    const float* __restrict__ s4, const float* __restrict__ s5,
    bf16* __restrict__ wdst, bf16* __restrict__ part, int* __restrict__ flags,
    bf16* __restrict__ sze, bf16* __restrict__ szm,
    bf16* __restrict__ ctxb, float* __restrict__ out)
{
  int bx = blockIdx.x;
  int t  = threadIdx.x;

  if (bx >= 768 + CVT_BLOCKS) {
    // ---------------- aux ----------------
    int q = bx - (768 + CVT_BLOCKS);
    if (q == 0) {            // entity size-emb table [128][32]
      for (int i = t; i < 128 * 32; i += 256)
        sze[i] = __hip_bfloat16(nsemb[(size_t)esizes[i >> 5] * 32 + (i & 31)]);
    } else if (q == 1) {     // mention size-emb table
      for (int i = t; i < 128 * 32; i += 256)
        szm[i] = __hip_bfloat16(esemb[(size_t)msizes[i >> 5] * 32 + (i & 31)]);
    } else if (q == 2) {     // bf16 cls-ctx rows, both batches
      __shared__ int s_cls;
      for (int b2 = 0; b2 < 2; b2++) {
        if (t == 0) s_cls = SS;
        __syncthreads();
        for (int s = t; s < SS; s += 256)
          if (input_ids[b2 * SS + s] == 101) atomicMin(&s_cls, s);
        __syncthreads();
        int ci = (s_cls == SS) ? 0 : s_cls;
        for (int hh = t; hh < HD; hh += 256)
          ctxb[(size_t)b2 * HD + hh] = __hip_bfloat16(emb[((size_t)b2 * SS + ci) * HD + hh]);
        __syncthreads();
      }
    } else {                 // zero d_out (3840 floats) for head atomics
      for (int i = t; i < 3840; i += 256) out[i] = 0.f;
    }
    return;
  }

  if (bx >= 768) {
    // ---------------- weight convert: 4096 elems (4 units of 1024) ----------------
    size_t i0 = (size_t)(bx - 768) * 4096;
    const float* s; size_t segoff;
    if      (i0 < WOFF_EMD) { s = s0; segoff = 0; }
    else if (i0 < WOFF_RW1) { s = s1; segoff = WOFF_EMD; }
    else if (i0 < WOFF_CW1) { s = s2; segoff = WOFF_RW1; }
    else if (i0 < WOFF_RW2) { s = s3; segoff = WOFF_CW1; }
    else if (i0 < WOFF_CW2) { s = s4; segoff = WOFF_RW2; }
    else                    { s = s5; segoff = WOFF_CW2; }
    #pragma unroll
    for (int j = 0; j < 4; j++) {
      size_t i = i0 + (size_t)j * 1024 + (size_t)t * 4;
      float4 v = *(const float4*)(s + (i - segoff));
      bf16 tmp[4] = { __hip_bfloat16(v.x), __hip_bfloat16(v.y),
                      __hip_bfloat16(v.z), __hip_bfloat16(v.w) };
      *(short4*)(wdst + i) = *(const short4*)tmp;
    }
    return;
  }

  // ---------------- pooling partials ----------------
  int g  = bx % 48;              // span group (8 spans)
  int b  = (bx / 48) & 1;        // batch
  int sp = bx / 96;              // S-split 0..7 (64 tokens each)
  int j0 = g * 8;

  const int* marr; int row0;
  if      (j0 < 64)  { marr = e_masks; row0 = b*64  +  j0;        }
  else if (j0 < 128) { marr = m_masks; row0 = b*64  + (j0-64);    }
  else if (j0 < 256) { marr = r_masks; row0 = b*128 + (j0-128);   }
  else               { marr = c_masks; row0 = b*128 + (j0-256);   }

  __shared__ unsigned s_pack[64];
  __shared__ unsigned s_any;
  if (t == 0) s_any = 0u;
  __syncthreads();

  int sbase = sp * 64;
  if (t < 64) {
    unsigned w = 0;
    #pragma unroll
    for (int k = 0; k < 8; k++) {
      int mm = marr[(size_t)(row0 + k) * SS + sbase + t];
      w |= (mm != 0 ? 1u : 0u) << k;
    }
    s_pack[t] = w;
    atomicOr(&s_any, w);
  }
  __syncthreads();

  float acc[8][3];
  #pragma unroll
  for (int k = 0; k < 8; k++)
    #pragma unroll
    for (int i = 0; i < 3; i++) acc[k][i] = -INFINITY;

  const float* ep = emb + ((size_t)b * SS + sbase) * HD + t;
  #pragma unroll 2
  for (int s = 0; s < 64; s++) {
    float v0 = ep[0];
    float v1 = ep[256];
    float v2 = ep[512];
    ep += HD;
    unsigned wm = __builtin_amdgcn_readfirstlane(s_pack[s]);  // block-uniform
    #pragma unroll
    for (int k = 0; k < 8; k++) {
      if (wm & (1u << k)) {          // scalar branch: taken ~50%
        acc[k][0] = fmaxf(acc[k][0], v0);
        acc[k][1] = fmaxf(acc[k][1], v1);
        acc[k][2] = fmaxf(acc[k][2], v2);
      }
    }
  }

  #pragma unroll
  for (int k = 0; k < 8; k++) {
    int sg = b * 384 + j0 + k;
    bf16* dst = part + ((size_t)sp * 768 + sg) * HD;
    dst[t]       = __hip_bfloat16(acc[k][0]);
    dst[t + 256] = __hip_bfloat16(acc[k][1]);
    dst[t + 512] = __hip_bfloat16(acc[k][2]);
  }
  if (t < 8) flags[sp * 768 + b * 384 + j0 + t] = (int)((s_any >> t) & 1u);
}

// ---------------------------------------------------------------------------
// Dispatch 2: combine the 8 S-split partials -> final bf16 pools / ctx.
// grid 768 (span-global), block 256 (3 h each).
// ---------------------------------------------------------------------------
__global__ __launch_bounds__(256) void k_combine(
    const bf16* __restrict__ part, const int* __restrict__ flags,
    bf16* __restrict__ epool, bf16* __restrict__ mpool,
    bf16* __restrict__ rctx, bf16* __restrict__ cctx)
{
  int sg = blockIdx.x;
  int b = sg / 384, j = sg % 384;
  int any = 0;
  #pragma unroll
  for (int sp = 0; sp < NSPLIT; sp++) any |= flags[sp * 768 + sg];
  #pragma unroll
  for (int i = 0; i < 3; i++) {
    int h = threadIdx.x + i * 256;
    float v = -INFINITY;
    #pragma unroll
    for (int sp = 0; sp < NSPLIT; sp++)
      v = fmaxf(v, (float)part[((size_t)sp * 768 + sg) * HD + h]);
    if      (j < 64)  epool[((size_t)b*64  + j)       * HD + h] = __hip_bfloat16(v);
    else if (j < 128) mpool[((size_t)b*64  + (j-64))  * HD + h] = __hip_bfloat16(v);
    else if (j < 256) rctx [((size_t)b*128 + (j-128)) * HD + h] = __hip_bfloat16(any ? v : 0.f);
    else              cctx [((size_t)b*128 + (j-256)) * HD + h] = __hip_bfloat16(any ? v : 0.f);
  }
}

// ---------------------------------------------------------------------------
// GEMM layer 1 with on-the-fly A gather (all segment boundaries are multiples
// of the 32-wide MFMA K-chunk). grid (8,24,4), block 256 = 4 waves K-split.
// Span problems (z<2): head fused via f32 atomicAdd. Rel (z>=2): store RH1/CH1.
// ---------------------------------------------------------------------------
struct P1 {
  const bf16 *ctx, *pool, *sz; const int* ridx;
  const short* W; const float* bias;
  bf16* C;                 // null for span problems
  const float *hw, *hb; float* outp;
  int is_rel, N, K, Mtiles;
};
struct P1x4 { P1 p[4]; };

__global__ __launch_bounds__(256, 2) void k_gemm1(P1x4 args)
{
  P1 g = args.p[blockIdx.z];
  int x = blockIdx.x;
  if (x >= g.Mtiles) return;
  int mt = x * 32, nt = blockIdx.y * 32;
  int wave = threadIdx.x >> 6, lane = threadIdx.x & 63;
  int lm = lane & 15, quad = lane >> 4;
  int K_ = g.K;

  const bf16 *g0[2], *g1[2], *g2[2], *g3[2], *g4[2];
  int rr[2] = { mt + lm, mt + 16 + lm };
  #pragma unroll
  for (int i = 0; i < 2; i++) {
    int r = rr[i];
    if (g.is_rel) {
      int b = r >> 7;
      int i0 = g.ridx[2 * r], i1 = g.ridx[2 * r + 1];
      g0[i] = g.ctx  + (size_t)r * HD;
      g1[i] = g.pool + (size_t)(b * 64 + i0) * HD;
      g2[i] = g.pool + (size_t)(b * 64 + i1) * HD;
      g3[i] = g.sz   + (size_t)(b * 64 + i0) * 32;
      g4[i] = g.sz   + (size_t)(b * 64 + i1) * 32;
    } else {
      g0[i] = g.ctx  + (size_t)(r >> 6) * HD;
      g1[i] = g.pool + (size_t)r * HD;
      g2[i] = g.sz   + (size_t)r * 32;
      g3[i] = g2[i]; g4[i] = g2[i];
    }
  }
  const short* w0p = g.W + (size_t)(nt + lm)      * K_ + quad * 8;
  const short* w1p = g.W + (size_t)(nt + 16 + lm) * K_ + quad * 8;

  f32x4 acc00 = {0.f,0.f,0.f,0.f}, acc01 = {0.f,0.f,0.f,0.f};
  f32x4 acc10 = {0.f,0.f,0.f,0.f}, acc11 = {0.f,0.f,0.f,0.f};

  for (int k32 = wave * 32; k32 < K_; k32 += 128) {
    const bf16 *b0, *b1;
    if      (k32 < 768)  { b0 = g0[0] + k32;          b1 = g0[1] + k32;          }
    else if (k32 < 1536) { b0 = g1[0] + (k32 - 768);  b1 = g1[1] + (k32 - 768);  }
    else if (k32 < 2304) { b0 = g2[0] + (k32 - 1536); b1 = g2[1] + (k32 - 1536); }
    else if (k32 < 2336) { b0 = g3[0] + (k32 - 2304); b1 = g3[1] + (k32 - 2304); }
    else                 { b0 = g4[0] + (k32 - 2336); b1 = g4[1] + (k32 - 2336); }
    short8 a0 = *(const short8*)((const short*)b0 + quad * 8);
    short8 a1 = *(const short8*)((const short*)b1 + quad * 8);
    short8 w0 = *(const short8*)(w0p + k32);
    short8 w1 = *(const short8*)(w1p + k32);
    acc00 = __builtin_amdgcn_mfma_f32_16x16x32_bf16(a0, w0, acc00, 0, 0, 0);
    acc01 = __builtin_amdgcn_mfma_f32_16x16x32_bf16(a0, w1, acc01, 0, 0, 0);
    acc10 = __builtin_amdgcn_mfma_f32_16x16x32_bf16(a1, w0, acc10, 0, 0, 0);
    acc11 = __builtin_amdgcn_mfma_f32_16x16x32_bf16(a1, w1, acc11, 0, 0, 0);
  }

  __shared__ float smem[4 * 32 * 32];
  #pragma unroll
  for (int reg = 0; reg < 4; reg++) {
    int r = quad * 4 + reg;
    smem[wave*1024 + r*32 + lm]             = acc00[reg];
    smem[wave*1024 + r*32 + 16 + lm]        = acc01[reg];
    smem[wave*1024 + (16 + r)*32 + lm]      = acc10[reg];
    smem[wave*1024 + (16 + r)*32 + 16 + lm] = acc11[reg];
  }
  __syncthreads();

  int c = threadIdx.x & 31;
  int rb = threadIdx.x >> 5;
  float bb = g.bias[nt + c];
  #pragma unroll
  for (int i = 0; i < 4; i++) {
    int r = rb + 8 * i;
    float v = smem[r*32 + c] + smem[1024 + r*32 + c] + smem[2048 + r*32 + c] + smem[3072 + r*32 + c];
    v = fmaxf(v + bb, 0.f);
    if (g.C) g.C[(size_t)(mt + r) * HD + nt + c] = __hip_bfloat16(v);
    else     smem[r*32 + c] = v;
  }
  __syncthreads();

  if (!g.C) {   // fused span head
    int r = threadIdx.x >> 3, oi = threadIdx.x & 7;
    for (int o = oi; o < g.N; o += 8) {
      float s = 0.f;
      #pragma unroll
      for (int cc = 0; cc < 32; cc++) {
        int c2 = (cc + r) & 31;
        s += smem[r*32 + c2] * g.hw[(size_t)o * HD + nt + c2];
      }
      if (blockIdx.y == 0) s += g.hb[o];
      atomicAdd(g.outp + (size_t)(mt + r) * g.N + o, s);
    }
  }
}

// ---------------------------------------------------------------------------
// GEMM layer 2 (contiguous A) + fused rel/cr heads. grid (8,24,2), block 256.
// ---------------------------------------------------------------------------
struct P2 { const short* A; const short* W; const float* bias;
            const float *hw, *hb; float* outp; int N; };
struct P2x2 { P2 p[2]; };

__global__ __launch_bounds__(256, 2) void k_gemm2(P2x2 args)
{
  P2 g = args.p[blockIdx.z];
  int mt = blockIdx.x * 32, nt = blockIdx.y * 32;
  int wave = threadIdx.x >> 6, lane = threadIdx.x & 63;
  int lm = lane & 15, quad = lane >> 4;

  const short* a0p = g.A + (size_t)(mt + lm)      * HD + quad * 8;
  const short* a1p = g.A + (size_t)(mt + 16 + lm) * HD + quad * 8;
  const short* w0p = g.W + (size_t)(nt + lm)      * HD + quad * 8;
  const short* w1p = g.W + (size_t)(nt + 16 + lm) * HD + quad * 8;

  f32x4 acc00 = {0.f,0.f,0.f,0.f}, acc01 = {0.f,0.f,0.f,0.f};
  f32x4 acc10 = {0.f,0.f,0.f,0.f}, acc11 = {0.f,0.f,0.f,0.f};

  for (int k32 = wave * 32; k32 < HD; k32 += 128) {
    short8 a0 = *(const short8*)(a0p + k32);
    short8 a1 = *(const short8*)(a1p + k32);
    short8 w0 = *(const short8*)(w0p + k32);
    short8 w1 = *(const short8*)(w1p + k32);
    acc00 = __builtin_amdgcn_mfma_f32_16x16x32_bf16(a0, w0, acc00, 0, 0, 0);
    acc01 = __builtin_amdgcn_mfma_f32_16x16x32_bf16(a0, w1, acc01, 0, 0, 0);
    acc10 = __builtin_amdgcn_mfma_f32_16x16x32_bf16(a1, w0, acc10, 0, 0, 0);
    acc11 = __builtin_amdgcn_mfma_f32_16x16x32_bf16(a1, w1, acc11, 0, 0, 0);
  }

  __shared__ float smem[4 * 32 * 32];
  #pragma unroll
  for (int reg = 0; reg < 4; reg++) {
    int r = quad * 4 + reg;
    smem[wave*1024 + r*32 + lm]             = acc00[reg];
    smem[wave*1024 + r*32 + 16 + lm]        = acc01[reg];
    smem[wave*1024 + (16 + r)*32 + lm]      = acc10[reg];
    smem[wave*1024 + (16 + r)*32 + 16 + lm] = acc11[reg];
  }
  __syncthreads();

  int c = threadIdx.x & 31;
  int rb = threadIdx.x >> 5;
  float bb = g.bias[nt + c];
  #pragma unroll
  for (int i = 0; i < 4; i++) {
    int r = rb + 8 * i;
    float v = smem[r*32 + c] + smem[1024 + r*32 + c] + smem[2048 + r*32 + c] + smem[3072 + r*32 + c];
    smem[r*32 + c] = fmaxf(v + bb, 0.f);
  }
  __syncthreads();

  int r = threadIdx.x >> 3, oi = threadIdx.x & 7;
  for (int o = oi; o < g.N; o += 8) {
    float s = 0.f;
    #pragma unroll
    for (int cc = 0; cc < 32; cc++) {
      int c2 = (cc + r) & 31;
      s += smem[r*32 + c2] * g.hw[(size_t)o * HD + nt + c2];
    }
    if (blockIdx.y == 0) s += g.hb[o];
    atomicAdd(g.outp + (size_t)(mt + r) * g.N + o, s);
  }
}

// ---------------------------------------------------------------------------
extern "C" void kernel_launch(void* const* d_in, const int* in_sizes, int n_in,
                              void* d_out, int out_size, void* d_ws, size_t ws_size,
                              hipStream_t stream)
{
  const int*   input_ids  = (const int*)d_in[0];
  const int*   e_masks    = (const int*)d_in[1];
  const int*   e_sizes    = (const int*)d_in[2];
  const int*   m_masks    = (const int*)d_in[3];
  const int*   m_sizes    = (const int*)d_in[4];
  const int*   relations  = (const int*)d_in[5];
  const int*   r_masks    = (const int*)d_in[6];
  const int*   references = (const int*)d_in[7];
  const int*   c_masks    = (const int*)d_in[8];
  const float* emb        = (const float*)d_in[9];
  const float* nsemb      = (const float*)d_in[10];
  const float* esemb      = (const float*)d_in[11];
  const float* ner_rep_w  = (const float*)d_in[12];
  const float* ner_rep_b  = (const float*)d_in[13];
  const float* ner_head_w = (const float*)d_in[14];
  const float* ner_head_b = (const float*)d_in[15];
  const float* emd_rep_w  = (const float*)d_in[16];
  const float* emd_rep_b  = (const float*)d_in[17];
  const float* emd_head_w = (const float*)d_in[18];
  const float* emd_head_b = (const float*)d_in[19];
  const float* rel_w1 = (const float*)d_in[20];
  const float* rel_b1 = (const float*)d_in[21];
  const float* rel_w2 = (const float*)d_in[22];
  const float* rel_b2 = (const float*)d_in[23];
  const float* rel_w3 = (const float*)d_in[24];
  const float* rel_b3 = (const float*)d_in[25];
  const float* cr_w1 = (const float*)d_in[26];
  const float* cr_b1 = (const float*)d_in[27];
  const float* cr_w2 = (const float*)d_in[28];
  const float* cr_b2 = (const float*)d_in[29];
  const float* cr_w3 = (const float*)d_in[30];
  const float* cr_b3 = (const float*)d_in[31];
  float* out = (float*)d_out;

  // ---- workspace carve ----
  bf16* wsb = (bf16*)d_ws;
  size_t ob = 0;
  bf16* WBF   = wsb + ob; ob += (size_t)W_TOT;
  bf16* PART  = wsb + ob; ob += (size_t)NSPLIT * 768 * HD;
  bf16* EPOOL = wsb + ob; ob += (size_t)128 * HD;
  bf16* MPOOL = wsb + ob; ob += (size_t)128 * HD;
  bf16* RCTX  = wsb + ob; ob += (size_t)256 * HD;
  bf16* CCTX  = wsb + ob; ob += (size_t)256 * HD;
  bf16* SZE   = wsb + ob; ob += (size_t)128 * 32;
  bf16* SZM   = wsb + ob; ob += (size_t)128 * 32;
  bf16* CTXB  = wsb + ob; ob += (size_t)2 * HD;
  bf16* RH1   = wsb + ob; ob += (size_t)256 * HD;
  bf16* CH1   = wsb + ob; ob += (size_t)256 * HD;
  int*  FLAGS = (int*)(wsb + ob); ob += (size_t)2 * NSPLIT * 768;

  // 1) pool partials + weight cvt + aux
  k_d1<<<D1_BLOCKS, 256, 0, stream>>>(
      e_masks, m_masks, r_masks, c_masks, emb, input_ids,
      e_sizes, m_sizes, nsemb, esemb,
      ner_rep_w, emd_rep_w, rel_w1, cr_w1, rel_w2, cr_w2,
      WBF, PART, FLAGS, SZE, SZM, CTXB, out);

  // 2) combine
  k_combine<<<768, 256, 0, stream>>>(PART, FLAGS, EPOOL, MPOOL, RCTX, CCTX);

  // 3) GEMM layer 1 (gathered A) + fused span heads
  P1x4 a1;
  a1.p[0] = { CTXB, EPOOL, SZE, nullptr,    (const short*)(WBF + WOFF_NER), ner_rep_b,
              nullptr, ner_head_w, ner_head_b, out,        0, 10, 1568, 4 };
  a1.p[1] = { CTXB, MPOOL, SZM, nullptr,    (const short*)(WBF + WOFF_EMD), emd_rep_b,
              nullptr, emd_head_w, emd_head_b, out + 3328, 0, 2,  1568, 4 };
  a1.p[2] = { RCTX, EPOOL, SZE, relations,  (const short*)(WBF + WOFF_RW1), rel_b1,
              RH1, nullptr, nullptr, nullptr,              1, 0,  2368, 8 };
  a1.p[3] = { CCTX, MPOOL, SZM, references, (const short*)(WBF + WOFF_CW1), cr_b1,
              CH1, nullptr, nullptr, nullptr,              1, 0,  2368, 8 };
  k_gemm1<<<dim3(8, 24, 4), 256, 0, stream>>>(a1);

  // 4) GEMM layer 2 + fused rel/cr heads
  P2x2 a2;
  a2.p[0] = { (const short*)RH1, (const short*)(WBF + WOFF_RW2), rel_b2,
              rel_w3, rel_b3, out + 1280, 8 };
  a2.p[1] = { (const short*)CH1, (const short*)(WBF + WOFF_CW2), cr_b2,
              cr_w3, cr_b3, out + 3584, 1 };
  k_gemm2<<<dim3(8, 24, 2), 256, 0, stream>>>(a2);
}

// Round 8
// 206.477 us; speedup vs baseline: 2.5463x; 1.0700x over previous
//
#include <hip/hip_runtime.h>
#include <hip/hip_bf16.h>

typedef __hip_bfloat16 bf16;
typedef __attribute__((ext_vector_type(8))) short short8;
typedef __attribute__((ext_vector_type(4))) float f32x4;

#define SS 512
#define HD 768
#define NEGC (-1e30f)
#define NSPLIT 16
#define TOK 32                       // SS / NSPLIT
#define POOL_BLOCKS 1536             // 48 groups * 2 batch * 16 splits
#define D1_BLOCKS (POOL_BLOCKS + 4)

// ---------------------------------------------------------------------------
// f32x8 -> bf16x8 in-register convert (for MFMA W operand)
// ---------------------------------------------------------------------------
__device__ __forceinline__ short8 cvt8(float4 a, float4 b)
{
  union { bf16 h[8]; short8 s; } u;
  u.h[0] = __hip_bfloat16(a.x); u.h[1] = __hip_bfloat16(a.y);
  u.h[2] = __hip_bfloat16(a.z); u.h[3] = __hip_bfloat16(a.w);
  u.h[4] = __hip_bfloat16(b.x); u.h[5] = __hip_bfloat16(b.y);
  u.h[6] = __hip_bfloat16(b.z); u.h[7] = __hip_bfloat16(b.w);
  return u.s;
}

// ---------------------------------------------------------------------------
// Dispatch 1: pool partials (bx<1536) | aux (last 4 blocks).
// Pool: 8 spans, 32 tokens (split sp of 16), 768 h = 3 consecutive h/thread
// (one dwordx3 load per token). Branch-free cndmask updates keep the 24
// accumulators in VGPRs (round-7's scalar-branch version demoted them to
// scratch: VGPR=16, VALU->VMEM swap, no win). Partials bf16.
// ---------------------------------------------------------------------------
__global__ __launch_bounds__(256) void k_d1(
    const int* __restrict__ e_masks, const int* __restrict__ m_masks,
    const int* __restrict__ r_masks, const int* __restrict__ c_masks,
    const float* __restrict__ emb, const int* __restrict__ input_ids,
    const int* __restrict__ esizes, const int* __restrict__ msizes,
    const float* __restrict__ nsemb, const float* __restrict__ esemb,
    bf16* __restrict__ part, int* __restrict__ flags,
    bf16* __restrict__ sze, bf16* __restrict__ szm,
    bf16* __restrict__ ctxb, float* __restrict__ out)
{
  int bx = blockIdx.x;
  int t  = threadIdx.x;

  if (bx >= POOL_BLOCKS) {
    // ---------------- aux ----------------
    int q = bx - POOL_BLOCKS;
    if (q == 0) {            // entity size-emb table [128][32] bf16
      for (int i = t; i < 128 * 32; i += 256)
        sze[i] = __hip_bfloat16(nsemb[(size_t)esizes[i >> 5] * 32 + (i & 31)]);
    } else if (q == 1) {     // mention size-emb table
      for (int i = t; i < 128 * 32; i += 256)
        szm[i] = __hip_bfloat16(esemb[(size_t)msizes[i >> 5] * 32 + (i & 31)]);
    } else if (q == 2) {     // bf16 cls-ctx rows, both batches
      __shared__ int s_cls;
      for (int b2 = 0; b2 < 2; b2++) {
        if (t == 0) s_cls = SS;
        __syncthreads();
        for (int s = t; s < SS; s += 256)
          if (input_ids[b2 * SS + s] == 101) atomicMin(&s_cls, s);
        __syncthreads();
        int ci = (s_cls == SS) ? 0 : s_cls;
        for (int hh = t; hh < HD; hh += 256)
          ctxb[(size_t)b2 * HD + hh] = __hip_bfloat16(emb[((size_t)b2 * SS + ci) * HD + hh]);
        __syncthreads();
      }
    } else {                 // zero d_out (3840 floats) for head atomics
      for (int i = t; i < 3840; i += 256) out[i] = 0.f;
    }
    return;
  }

  // ---------------- pooling partials ----------------
  int g  = bx % 48;              // span group (8 spans)
  int b  = (bx / 48) & 1;        // batch
  int sp = bx / 96;              // S-split 0..15 (32 tokens each)
  int j0 = g * 8;

  const int* marr; int row0;
  if      (j0 < 64)  { marr = e_masks; row0 = b*64  +  j0;        }
  else if (j0 < 128) { marr = m_masks; row0 = b*64  + (j0-64);    }
  else if (j0 < 256) { marr = r_masks; row0 = b*128 + (j0-128);   }
  else               { marr = c_masks; row0 = b*128 + (j0-256);   }

  __shared__ unsigned s_pack[TOK];
  __shared__ unsigned s_any;
  if (t == 0) s_any = 0u;
  __syncthreads();

  int sbase = sp * TOK;
  if (t < TOK) {
    unsigned w = 0;
    #pragma unroll
    for (int k = 0; k < 8; k++) {
      int mm = marr[(size_t)(row0 + k) * SS + sbase + t];
      w |= (mm != 0 ? 1u : 0u) << k;
    }
    s_pack[t] = w;
    atomicOr(&s_any, w);
  }
  __syncthreads();

  float a0[8], a1[8], a2[8];
  #pragma unroll
  for (int k = 0; k < 8; k++) { a0[k] = -INFINITY; a1[k] = -INFINITY; a2[k] = -INFINITY; }

  // 3 consecutive h per thread -> one 12B load per token
  const float* ep = emb + ((size_t)b * SS + sbase) * HD + t * 3;
  #pragma unroll 2
  for (int s = 0; s < TOK; s++) {
    float v0 = ep[0];
    float v1 = ep[1];
    float v2 = ep[2];
    ep += HD;
    unsigned wm = s_pack[s];
    #pragma unroll
    for (int k = 0; k < 8; k++) {
      float add = (wm & (1u << k)) ? 0.f : NEGC;
      a0[k] = fmaxf(a0[k], v0 + add);
      a1[k] = fmaxf(a1[k], v1 + add);
      a2[k] = fmaxf(a2[k], v2 + add);
    }
  }

  #pragma unroll
  for (int k = 0; k < 8; k++) {
    int sg = b * 384 + j0 + k;
    bf16* dst = part + ((size_t)sp * 768 + sg) * HD + t * 3;
    dst[0] = __hip_bfloat16(a0[k]);
    dst[1] = __hip_bfloat16(a1[k]);
    dst[2] = __hip_bfloat16(a2[k]);
  }
  if (t < 8) flags[sp * 768 + b * 384 + j0 + t] = (int)((s_any >> t) & 1u);
}

// ---------------------------------------------------------------------------
// Dispatch 2: combine the 16 S-split partials -> final bf16 pools / ctx.
// grid 768 (span-global), block 256 (3 consecutive h each).
// ---------------------------------------------------------------------------
__global__ __launch_bounds__(256) void k_combine(
    const bf16* __restrict__ part, const int* __restrict__ flags,
    bf16* __restrict__ epool, bf16* __restrict__ mpool,
    bf16* __restrict__ rctx, bf16* __restrict__ cctx)
{
  int sg = blockIdx.x;
  int b = sg / 384, j = sg % 384;
  int any = 0;
  #pragma unroll
  for (int sp = 0; sp < NSPLIT; sp++) any |= flags[sp * 768 + sg];

  int h = threadIdx.x * 3;
  float v0 = -INFINITY, v1 = -INFINITY, v2 = -INFINITY;
  #pragma unroll
  for (int sp = 0; sp < NSPLIT; sp++) {
    const bf16* src = part + ((size_t)sp * 768 + sg) * HD + h;
    v0 = fmaxf(v0, (float)src[0]);
    v1 = fmaxf(v1, (float)src[1]);
    v2 = fmaxf(v2, (float)src[2]);
  }
  bf16* dst;
  if      (j < 64)  { dst = epool + ((size_t)b*64  + j)       * HD + h; }
  else if (j < 128) { dst = mpool + ((size_t)b*64  + (j-64))  * HD + h; }
  else if (j < 256) { dst = rctx  + ((size_t)b*128 + (j-128)) * HD + h;
                      if (!any) { v0 = 0.f; v1 = 0.f; v2 = 0.f; } }
  else              { dst = cctx  + ((size_t)b*128 + (j-256)) * HD + h;
                      if (!any) { v0 = 0.f; v1 = 0.f; v2 = 0.f; } }
  dst[0] = __hip_bfloat16(v0);
  dst[1] = __hip_bfloat16(v1);
  dst[2] = __hip_bfloat16(v2);
}

// ---------------------------------------------------------------------------
// GEMM layer 1: A gathered bf16, W loaded f32 + in-register cvt (no WBF
// round-trip). grid (8,24,4), block 256 = 4 waves K-split + LDS reduce.
// Span problems (z<2): head fused via f32 atomicAdd. Rel (z>=2): store RH1/CH1.
// ---------------------------------------------------------------------------
struct P1 {
  const bf16 *ctx, *pool, *sz; const int* ridx;
  const float* W; const float* bias;
  bf16* C;                 // null for span problems
  const float *hw, *hb; float* outp;
  int is_rel, N, K, Mtiles;
};
struct P1x4 { P1 p[4]; };

__global__ __launch_bounds__(256, 2) void k_gemm1(P1x4 args)
{
  P1 g = args.p[blockIdx.z];
  int x = blockIdx.x;
  if (x >= g.Mtiles) return;
  int mt = x * 32, nt = blockIdx.y * 32;
  int wave = threadIdx.x >> 6, lane = threadIdx.x & 63;
  int lm = lane & 15, quad = lane >> 4;
  int K_ = g.K;

  const bf16 *g0[2], *g1[2], *g2[2], *g3[2], *g4[2];
  int rr[2] = { mt + lm, mt + 16 + lm };
  #pragma unroll
  for (int i = 0; i < 2; i++) {
    int r = rr[i];
    if (g.is_rel) {
      int b = r >> 7;
      int i0 = g.ridx[2 * r], i1 = g.ridx[2 * r + 1];
      g0[i] = g.ctx  + (size_t)r * HD;
      g1[i] = g.pool + (size_t)(b * 64 + i0) * HD;
      g2[i] = g.pool + (size_t)(b * 64 + i1) * HD;
      g3[i] = g.sz   + (size_t)(b * 64 + i0) * 32;
      g4[i] = g.sz   + (size_t)(b * 64 + i1) * 32;
    } else {
      g0[i] = g.ctx  + (size_t)(r >> 6) * HD;
      g1[i] = g.pool + (size_t)r * HD;
      g2[i] = g.sz   + (size_t)r * 32;
      g3[i] = g2[i]; g4[i] = g2[i];
    }
  }
  const float* w0p = g.W + (size_t)(nt + lm)      * K_ + quad * 8;
  const float* w1p = g.W + (size_t)(nt + 16 + lm) * K_ + quad * 8;

  f32x4 acc00 = {0.f,0.f,0.f,0.f}, acc01 = {0.f,0.f,0.f,0.f};
  f32x4 acc10 = {0.f,0.f,0.f,0.f}, acc11 = {0.f,0.f,0.f,0.f};

  for (int k32 = wave * 32; k32 < K_; k32 += 128) {
    const bf16 *b0, *b1;
    if      (k32 < 768)  { b0 = g0[0] + k32;          b1 = g0[1] + k32;          }
    else if (k32 < 1536) { b0 = g1[0] + (k32 - 768);  b1 = g1[1] + (k32 - 768);  }
    else if (k32 < 2304) { b0 = g2[0] + (k32 - 1536); b1 = g2[1] + (k32 - 1536); }
    else if (k32 < 2336) { b0 = g3[0] + (k32 - 2304); b1 = g3[1] + (k32 - 2304); }
    else                 { b0 = g4[0] + (k32 - 2336); b1 = g4[1] + (k32 - 2336); }
    short8 a0 = *(const short8*)((const short*)b0 + quad * 8);
    short8 a1 = *(const short8*)((const short*)b1 + quad * 8);
    const float* wq0 = w0p + k32;
    const float* wq1 = w1p + k32;
    short8 w0 = cvt8(*(const float4*)wq0, *(const float4*)(wq0 + 4));
    short8 w1 = cvt8(*(const float4*)wq1, *(const float4*)(wq1 + 4));
    acc00 = __builtin_amdgcn_mfma_f32_16x16x32_bf16(a0, w0, acc00, 0, 0, 0);
    acc01 = __builtin_amdgcn_mfma_f32_16x16x32_bf16(a0, w1, acc01, 0, 0, 0);
    acc10 = __builtin_amdgcn_mfma_f32_16x16x32_bf16(a1, w0, acc10, 0, 0, 0);
    acc11 = __builtin_amdgcn_mfma_f32_16x16x32_bf16(a1, w1, acc11, 0, 0, 0);
  }

  __shared__ float smem[4 * 32 * 32];
  #pragma unroll
  for (int reg = 0; reg < 4; reg++) {
    int r = quad * 4 + reg;
    smem[wave*1024 + r*32 + lm]             = acc00[reg];
    smem[wave*1024 + r*32 + 16 + lm]        = acc01[reg];
    smem[wave*1024 + (16 + r)*32 + lm]      = acc10[reg];
    smem[wave*1024 + (16 + r)*32 + 16 + lm] = acc11[reg];
  }
  __syncthreads();

  int c = threadIdx.x & 31;
  int rb = threadIdx.x >> 5;
  float bb = g.bias[nt + c];
  #pragma unroll
  for (int i = 0; i < 4; i++) {
    int r = rb + 8 * i;
    float v = smem[r*32 + c] + smem[1024 + r*32 + c] + smem[2048 + r*32 + c] + smem[3072 + r*32 + c];
    v = fmaxf(v + bb, 0.f);
    if (g.C) g.C[(size_t)(mt + r) * HD + nt + c] = __hip_bfloat16(v);
    else     smem[r*32 + c] = v;
  }
  __syncthreads();

  if (!g.C) {   // fused span head
    int r = threadIdx.x >> 3, oi = threadIdx.x & 7;
    for (int o = oi; o < g.N; o += 8) {
      float s = 0.f;
      #pragma unroll
      for (int cc = 0; cc < 32; cc++) {
        int c2 = (cc + r) & 31;
        s += smem[r*32 + c2] * g.hw[(size_t)o * HD + nt + c2];
      }
      if (blockIdx.y == 0) s += g.hb[o];
      atomicAdd(g.outp + (size_t)(mt + r) * g.N + o, s);
    }
  }
}

// ---------------------------------------------------------------------------
// GEMM layer 2: A bf16 contiguous, W f32 + in-register cvt, fused rel/cr
// heads. grid (8,24,2), block 256.
// ---------------------------------------------------------------------------
struct P2 { const short* A; const float* W; const float* bias;
            const float *hw, *hb; float* outp; int N; };
struct P2x2 { P2 p[2]; };

__global__ __launch_bounds__(256, 2) void k_gemm2(P2x2 args)
{
  P2 g = args.p[blockIdx.z];
  int mt = blockIdx.x * 32, nt = blockIdx.y * 32;
  int wave = threadIdx.x >> 6, lane = threadIdx.x & 63;
  int lm = lane & 15, quad = lane >> 4;

  const short* a0p = g.A + (size_t)(mt + lm)      * HD + quad * 8;
  const short* a1p = g.A + (size_t)(mt + 16 + lm) * HD + quad * 8;
  const float* w0p = g.W + (size_t)(nt + lm)      * HD + quad * 8;
  const float* w1p = g.W + (size_t)(nt + 16 + lm) * HD + quad * 8;

  f32x4 acc00 = {0.f,0.f,0.f,0.f}, acc01 = {0.f,0.f,0.f,0.f};
  f32x4 acc10 = {0.f,0.f,0.f,0.f}, acc11 = {0.f,0.f,0.f,0.f};

  for (int k32 = wave * 32; k32 < HD; k32 += 128) {
    short8 a0 = *(const short8*)(a0p + k32);
    short8 a1 = *(const short8*)(a1p + k32);
    short8 w0 = cvt8(*(const float4*)(w0p + k32), *(const float4*)(w0p + k32 + 4));
    short8 w1 = cvt8(*(const float4*)(w1p + k32), *(const float4*)(w1p + k32 + 4));
    acc00 = __builtin_amdgcn_mfma_f32_16x16x32_bf16(a0, w0, acc00, 0, 0, 0);
    acc01 = __builtin_amdgcn_mfma_f32_16x16x32_bf16(a0, w1, acc01, 0, 0, 0);
    acc10 = __builtin_amdgcn_mfma_f32_16x16x32_bf16(a1, w0, acc10, 0, 0, 0);
    acc11 = __builtin_amdgcn_mfma_f32_16x16x32_bf16(a1, w1, acc11, 0, 0, 0);
  }

  __shared__ float smem[4 * 32 * 32];
  #pragma unroll
  for (int reg = 0; reg < 4; reg++) {
    int r = quad * 4 + reg;
    smem[wave*1024 + r*32 + lm]             = acc00[reg];
    smem[wave*1024 + r*32 + 16 + lm]        = acc01[reg];
    smem[wave*1024 + (16 + r)*32 + lm]      = acc10[reg];
    smem[wave*1024 + (16 + r)*32 + 16 + lm] = acc11[reg];
  }
  __syncthreads();

  int c = threadIdx.x & 31;
  int rb = threadIdx.x >> 5;
  float bb = g.bias[nt + c];
  #pragma unroll
  for (int i = 0; i < 4; i++) {
    int r = rb + 8 * i;
    float v = smem[r*32 + c] + smem[1024 + r*32 + c] + smem[2048 + r*32 + c] + smem[3072 + r*32 + c];
    smem[r*32 + c] = fmaxf(v + bb, 0.f);
  }
  __syncthreads();

  int r = threadIdx.x >> 3, oi = threadIdx.x & 7;
  for (int o = oi; o < g.N; o += 8) {
    float s = 0.f;
    #pragma unroll
    for (int cc = 0; cc < 32; cc++) {
      int c2 = (cc + r) & 31;
      s += smem[r*32 + c2] * g.hw[(size_t)o * HD + nt + c2];
    }
    if (blockIdx.y == 0) s += g.hb[o];
    atomicAdd(g.outp + (size_t)(mt + r) * g.N + o, s);
  }
}

// ---------------------------------------------------------------------------
extern "C" void kernel_launch(void* const* d_in, const int* in_sizes, int n_in,
                              void* d_out, int out_size, void* d_ws, size_t ws_size,
                              hipStream_t stream)
{
  const int*   input_ids  = (const int*)d_in[0];
  const int*   e_masks    = (const int*)d_in[1];
  const int*   e_sizes    = (const int*)d_in[2];
  const int*   m_masks    = (const int*)d_in[3];
  const int*   m_sizes    = (const int*)d_in[4];
  const int*   relations  = (const int*)d_in[5];
  const int*   r_masks    = (const int*)d_in[6];
  const int*   references = (const int*)d_in[7];
  const int*   c_masks    = (const int*)d_in[8];
  const float* emb        = (const float*)d_in[9];
  const float* nsemb      = (const float*)d_in[10];
  const float* esemb      = (const float*)d_in[11];
  const float* ner_rep_w  = (const float*)d_in[12];
  const float* ner_rep_b  = (const float*)d_in[13];
  const float* ner_head_w = (const float*)d_in[14];
  const float* ner_head_b = (const float*)d_in[15];
  const float* emd_rep_w  = (const float*)d_in[16];
  const float* emd_rep_b  = (const float*)d_in[17];
  const float* emd_head_w = (const float*)d_in[18];
  const float* emd_head_b = (const float*)d_in[19];
  const float* rel_w1 = (const float*)d_in[20];
  const float* rel_b1 = (const float*)d_in[21];
  const float* rel_w2 = (const float*)d_in[22];
  const float* rel_b2 = (const float*)d_in[23];
  const float* rel_w3 = (const float*)d_in[24];
  const float* rel_b3 = (const float*)d_in[25];
  const float* cr_w1 = (const float*)d_in[26];
  const float* cr_b1 = (const float*)d_in[27];
  const float* cr_w2 = (const float*)d_in[28];
  const float* cr_b2 = (const float*)d_in[29];
  const float* cr_w3 = (const float*)d_in[30];
  const float* cr_b3 = (const float*)d_in[31];
  float* out = (float*)d_out;

  // ---- workspace carve ----
  bf16* wsb = (bf16*)d_ws;
  size_t ob = 0;
  bf16* PART  = wsb + ob; ob += (size_t)NSPLIT * 768 * HD;
  bf16* EPOOL = wsb + ob; ob += (size_t)128 * HD;
  bf16* MPOOL = wsb + ob; ob += (size_t)128 * HD;
  bf16* RCTX  = wsb + ob; ob += (size_t)256 * HD;
  bf16* CCTX  = wsb + ob; ob += (size_t)256 * HD;
  bf16* SZE   = wsb + ob; ob += (size_t)128 * 32;
  bf16* SZM   = wsb + ob; ob += (size_t)128 * 32;
  bf16* CTXB  = wsb + ob; ob += (size_t)2 * HD;
  bf16* RH1   = wsb + ob; ob += (size_t)256 * HD;
  bf16* CH1   = wsb + ob; ob += (size_t)256 * HD;
  int*  FLAGS = (int*)(wsb + ob); ob += (size_t)2 * NSPLIT * 768;

  // 1) pool partials + aux
  k_d1<<<D1_BLOCKS, 256, 0, stream>>>(
      e_masks, m_masks, r_masks, c_masks, emb, input_ids,
      e_sizes, m_sizes, nsemb, esemb,
      PART, FLAGS, SZE, SZM, CTXB, out);

  // 2) combine
  k_combine<<<768, 256, 0, stream>>>(PART, FLAGS, EPOOL, MPOOL, RCTX, CCTX);

  // 3) GEMM layer 1 (gathered A, f32 W) + fused span heads
  P1x4 a1;
  a1.p[0] = { CTXB, EPOOL, SZE, nullptr,    ner_rep_w, ner_rep_b,
              nullptr, ner_head_w, ner_head_b, out,        0, 10, 1568, 4 };
  a1.p[1] = { CTXB, MPOOL, SZM, nullptr,    emd_rep_w, emd_rep_b,
              nullptr, emd_head_w, emd_head_b, out + 3328, 0, 2,  1568, 4 };
  a1.p[2] = { RCTX, EPOOL, SZE, relations,  rel_w1, rel_b1,
              RH1, nullptr, nullptr, nullptr,              1, 0,  2368, 8 };
  a1.p[3] = { CCTX, MPOOL, SZM, references, cr_w1, cr_b1,
              CH1, nullptr, nullptr, nullptr,              1, 0,  2368, 8 };
  k_gemm1<<<dim3(8, 24, 4), 256, 0, stream>>>(a1);

  // 4) GEMM layer 2 (f32 W) + fused rel/cr heads
  P2x2 a2;
  a2.p[0] = { (const short*)RH1, rel_w2, rel_b2, rel_w3, rel_b3, out + 1280, 8 };
  a2.p[1] = { (const short*)CH1, cr_w2,  cr_b2,  cr_w3,  cr_b3,  out + 3584, 1 };
  k_gemm2<<<dim3(8, 24, 2), 256, 0, stream>>>(a2);
}